// Round 2
// baseline (1000.414 us; speedup 1.0000x reference)
//
#include <hip/hip_runtime.h>
#include <hip/hip_bf16.h>

// Mamba2 layer, MI355X/gfx950. Round 1: fix crash — ws overlays (401->155MB),
// 16B-aligned LDS, split GEMM1 epilogue, bf16 ybuf with in-place gate_norm.

#define D_MODEL   2048
#define D_STATE   128
#define HEADDIM   64
#define CHUNK     256
#define D_INNER   4096
#define NHEADS    64
#define CONV_DIM  4352
#define D_IN_PROJ 8512
#define SEQLEN    2048
#define NC        8
#define ROWSTOT   4096      // BATCH*SEQLEN
#define NPAD      8576      // D_IN_PROJ padded to 128
#define RMS_EPS   1e-5f

// ---- workspace layout (byte offsets), lifetime-overlaid ----
// S_A: win_bf(steps1-3) -> x_bf(5-7) -> prevb(8-9)@+0, wout_bf(10-12)@+16MB
#define OFF_WIN   0ull
#define OFF_XBF   0ull
#define OFF_PREV  0ull
#define OFF_WOUT  16777216ull
// S_B: u_bf(1-3) -> dtv/dacs/Bbf/Cbf/CBb (4+)
#define OFF_UBF   35127296ull
#define OFF_DTV   35127296ull
#define OFF_DACS  36175872ull
#define OFF_BBF   37224448ull
#define OFF_CBF   38273024ull
#define OFF_CB    39321600ull
// S_C: xbc_bf(3-5) -> states(7-8)
#define OFF_XBC   51904512ull
#define OFF_STATE 51904512ull
// S_D: z_bf(3-11)
#define OFF_ZBF   87556096ull
// S_E: dt_raw(3-4) -> ybuf(7-12, in-place gate_norm)
#define OFF_DTRAW 121110528ull
#define OFF_YBUF  121110528ull
#define WS_NEEDED 154664960ull

typedef __hip_bfloat16 bf16;
typedef __bf16 bfrag8 __attribute__((ext_vector_type(8)));
typedef float  f32x4v __attribute__((ext_vector_type(4)));

__device__ __forceinline__ f32x4v mfma16(bfrag8 a, bfrag8 b, f32x4v c) {
  return __builtin_amdgcn_mfma_f32_16x16x32_bf16(a, b, c, 0, 0, 0);
}

__device__ __forceinline__ void gload_lds16(const void* g, void* l) {
  __builtin_amdgcn_global_load_lds((const __attribute__((address_space(1))) void*)g,
                                   (__attribute__((address_space(3))) void*)l, 16, 0, 0);
}

__device__ __forceinline__ bf16 f2b(float x) { return __float2bfloat16(x); }
__device__ __forceinline__ float b2f(bf16 x) { return __bfloat162float(x); }
__device__ __forceinline__ float siluf(float x) { return x / (1.f + __expf(-x)); }

// ---------------- cast kernels ----------------
__global__ __launch_bounds__(256) void cast_kernel(const float* __restrict__ in,
                                                   bf16* __restrict__ out, long n4) {
  long i = (long)blockIdx.x * 256 + threadIdx.x;
  if (i >= n4) return;
  float4 v = ((const float4*)in)[i];
  bf16* o = out + i * 4;
  o[0] = f2b(v.x); o[1] = f2b(v.y); o[2] = f2b(v.z); o[3] = f2b(v.w);
}

__global__ __launch_bounds__(256) void cast_pad_kernel(const float* __restrict__ in,
                                                       bf16* __restrict__ out) {
  long i = (long)blockIdx.x * 256 + threadIdx.x;
  long e = i * 4;
  if (e >= (long)NPAD * D_MODEL) return;
  long row = e / D_MODEL;
  bf16* o = out + e;
  if (row < D_IN_PROJ) {
    float4 v = *(const float4*)(in + e);
    o[0] = f2b(v.x); o[1] = f2b(v.y); o[2] = f2b(v.z); o[3] = f2b(v.w);
  } else {
    bf16 z = f2b(0.f);
    o[0] = z; o[1] = z; o[2] = z; o[3] = z;
  }
}

// ---------------- GEMM1: zxbcdt, epilogue split into z / xBC / dt_raw ----------------
__global__ __launch_bounds__(256) void gemm1_kernel(const bf16* __restrict__ A,
                                                    const bf16* __restrict__ B,
                                                    bf16* __restrict__ zb,
                                                    bf16* __restrict__ xbc,
                                                    float* __restrict__ dtraw) {
  __shared__ __align__(16) bf16 As[128 * 32];
  __shared__ __align__(16) bf16 Bs[128 * 32];
  int tid = threadIdx.x, lane = tid & 63, w = tid >> 6;
  int wr = w >> 1, wc = w & 1, r16 = lane & 15, q = lane >> 4;
  long row0 = (long)blockIdx.y * 128, col0 = (long)blockIdx.x * 128;
  const int K = D_MODEL;
  f32x4v zero4 = {0.f, 0.f, 0.f, 0.f};
  f32x4v acc[4][4];
#pragma unroll
  for (int i = 0; i < 4; ++i)
#pragma unroll
    for (int j = 0; j < 4; ++j) acc[i][j] = zero4;

  for (int kt = 0; kt < K; kt += 32) {
    __syncthreads();
#pragma unroll
    for (int j = 0; j < 2; ++j) {
      int ci = (j * 4 + w) * 64 + lane;
      int r = ci >> 2, o8 = (ci & 3) * 8;
      gload_lds16(A + (row0 + r) * (long)K + kt + o8, (char*)As + (j * 4 + w) * 1024);
      gload_lds16(B + (col0 + r) * (long)K + kt + o8, (char*)Bs + (j * 4 + w) * 1024);
    }
    __syncthreads();
    bfrag8 af[4], bfv[4];
#pragma unroll
    for (int i = 0; i < 4; ++i) af[i]  = *(const bfrag8*)(As + (wr * 64 + i * 16 + r16) * 32 + q * 8);
#pragma unroll
    for (int i = 0; i < 4; ++i) bfv[i] = *(const bfrag8*)(Bs + (wc * 64 + i * 16 + r16) * 32 + q * 8);
#pragma unroll
    for (int i = 0; i < 4; ++i)
#pragma unroll
      for (int j = 0; j < 4; ++j) acc[i][j] = mfma16(af[i], bfv[j], acc[i][j]);
  }
#pragma unroll
  for (int i = 0; i < 4; ++i)
#pragma unroll
    for (int j = 0; j < 4; ++j) {
      long col = col0 + wc * 64 + j * 16 + r16;
#pragma unroll
      for (int r = 0; r < 4; ++r) {
        long row = row0 + wr * 64 + i * 16 + q * 4 + r;
        float v = acc[i][j][r];
        if (col < D_INNER)                       zb[row * D_INNER + col] = f2b(v);
        else if (col < D_INNER + CONV_DIM)       xbc[row * CONV_DIM + (col - D_INNER)] = f2b(v);
        else if (col < D_IN_PROJ)                dtraw[row * NHEADS + (col - D_INNER - CONV_DIM)] = v;
      }
    }
}

// ---------------- GEMM2: out[M,N] = A[M,K] * B[N,K]^T, fp32 out ----------------
__global__ __launch_bounds__(256) void gemm2_kernel(const bf16* __restrict__ A,
                                                    const bf16* __restrict__ B,
                                                    float* __restrict__ C) {
  __shared__ __align__(16) bf16 As[128 * 32];
  __shared__ __align__(16) bf16 Bs[128 * 32];
  int tid = threadIdx.x, lane = tid & 63, w = tid >> 6;
  int wr = w >> 1, wc = w & 1, r16 = lane & 15, q = lane >> 4;
  long row0 = (long)blockIdx.y * 128, col0 = (long)blockIdx.x * 128;
  const int K = D_INNER, ldc = D_MODEL;
  f32x4v zero4 = {0.f, 0.f, 0.f, 0.f};
  f32x4v acc[4][4];
#pragma unroll
  for (int i = 0; i < 4; ++i)
#pragma unroll
    for (int j = 0; j < 4; ++j) acc[i][j] = zero4;

  for (int kt = 0; kt < K; kt += 32) {
    __syncthreads();
#pragma unroll
    for (int j = 0; j < 2; ++j) {
      int ci = (j * 4 + w) * 64 + lane;
      int r = ci >> 2, o8 = (ci & 3) * 8;
      gload_lds16(A + (row0 + r) * (long)K + kt + o8, (char*)As + (j * 4 + w) * 1024);
      gload_lds16(B + (col0 + r) * (long)K + kt + o8, (char*)Bs + (j * 4 + w) * 1024);
    }
    __syncthreads();
    bfrag8 af[4], bfv[4];
#pragma unroll
    for (int i = 0; i < 4; ++i) af[i]  = *(const bfrag8*)(As + (wr * 64 + i * 16 + r16) * 32 + q * 8);
#pragma unroll
    for (int i = 0; i < 4; ++i) bfv[i] = *(const bfrag8*)(Bs + (wc * 64 + i * 16 + r16) * 32 + q * 8);
#pragma unroll
    for (int i = 0; i < 4; ++i)
#pragma unroll
      for (int j = 0; j < 4; ++j) acc[i][j] = mfma16(af[i], bfv[j], acc[i][j]);
  }
#pragma unroll
  for (int i = 0; i < 4; ++i)
#pragma unroll
    for (int j = 0; j < 4; ++j)
#pragma unroll
      for (int r = 0; r < 4; ++r) {
        long row = row0 + wr * 64 + i * 16 + q * 4 + r;
        long col = col0 + wc * 64 + j * 16 + r16;
        C[row * ldc + col] = acc[i][j][r];
      }
}

// ---------------- dt softplus + per-chunk cumsum of dt*A ----------------
__global__ __launch_bounds__(256) void dt_scan_kernel(const float* __restrict__ dtraw,
    const float* __restrict__ dt_bias, const float* __restrict__ A_log,
    float* __restrict__ dtv_buf, float* __restrict__ dacs_buf) {
  int blk = blockIdx.x;                       // b*512 + h*8 + c
  int c = blk & 7, h = (blk >> 3) & 63, b = blk >> 9;
  int s = threadIdx.x;
  long row = (long)b * SEQLEN + c * CHUNK + s;
  float raw = dtraw[row * NHEADS + h] + dt_bias[h];
  float dtv = fmaxf(raw, 0.f) + log1pf(__expf(-fabsf(raw)));   // stable softplus
  float A = -__expf(A_log[h]);
  __shared__ __align__(16) float sc[CHUNK];
  sc[s] = dtv * A;
  __syncthreads();
  for (int off = 1; off < CHUNK; off <<= 1) {
    float v = (s >= off) ? sc[s - off] : 0.f;
    __syncthreads();
    sc[s] += v;
    __syncthreads();
  }
  long o = ((long)(b * NHEADS + h) * NC + c) * CHUNK + s;
  dtv_buf[o] = dtv;
  dacs_buf[o] = sc[s];
}

// ---------------- depthwise conv1d + SiLU, split to x/B/C bf16 ----------------
__global__ __launch_bounds__(256) void conv_kernel(const bf16* __restrict__ xbc,
    const float* __restrict__ conv_w, const float* __restrict__ conv_b,
    bf16* __restrict__ xo, bf16* __restrict__ Bo, bf16* __restrict__ Co) {
  int cidx = blockIdx.x * 256 + threadIdx.x;  // 0..4351
  int l = blockIdx.y, b = blockIdx.z;
  float4 wv = *(const float4*)(conv_w + cidx * 4);
  float acc = conv_b[cidx];
  const bf16* base = xbc + (long)b * SEQLEN * CONV_DIM + cidx;
  float wk[4] = {wv.x, wv.y, wv.z, wv.w};
#pragma unroll
  for (int k = 0; k < 4; ++k) {
    int ls = l - 3 + k;
    if (ls >= 0) acc += wk[k] * b2f(base[(long)ls * CONV_DIM]);
  }
  bf16 o = f2b(siluf(acc));
  long rowo = (long)b * SEQLEN + l;
  if (cidx < D_INNER)                 xo[rowo * D_INNER + cidx] = o;
  else if (cidx < D_INNER + D_STATE)  Bo[rowo * D_STATE + (cidx - D_INNER)] = o;
  else                                Co[rowo * D_STATE + (cidx - D_INNER - D_STATE)] = o;
}

// ---------------- CB[l,s] = sum_n C[l,n]*B[s,n], per (b,chunk) ----------------
__global__ __launch_bounds__(256) void cb_kernel(const bf16* __restrict__ Cg,
                                                 const bf16* __restrict__ Bg,
                                                 float* __restrict__ CB) {
  int blk = blockIdx.x;                        // b*8 + c
  int c = blk & 7, b = blk >> 3;
  int tid = threadIdx.x, lane = tid & 63, w = tid >> 6, r16 = lane & 15, q = lane >> 4;
  const bf16* Cb = Cg + ((long)b * SEQLEN + c * CHUNK) * D_STATE;
  const bf16* Bb = Bg + ((long)b * SEQLEN + c * CHUNK) * D_STATE;
  bfrag8 af[4][4];
#pragma unroll
  for (int lt = 0; lt < 4; ++lt)
#pragma unroll
    for (int kk = 0; kk < 4; ++kk)
      af[lt][kk] = *(const bfrag8*)(Cb + (long)(w * 64 + lt * 16 + r16) * D_STATE + kk * 32 + q * 8);
  float* CBb = CB + (long)blk * CHUNK * CHUNK;
  f32x4v zero4 = {0.f, 0.f, 0.f, 0.f};
  for (int st = 0; st < 16; ++st) {
    f32x4v acc[4] = {zero4, zero4, zero4, zero4};
#pragma unroll
    for (int kk = 0; kk < 4; ++kk) {
      bfrag8 bfv = *(const bfrag8*)(Bb + (long)(st * 16 + r16) * D_STATE + kk * 32 + q * 8);
#pragma unroll
      for (int lt = 0; lt < 4; ++lt) acc[lt] = mfma16(af[lt][kk], bfv, acc[lt]);
    }
#pragma unroll
    for (int lt = 0; lt < 4; ++lt)
#pragma unroll
      for (int r = 0; r < 4; ++r)
        CBb[(long)(w * 64 + lt * 16 + q * 4 + r) * CHUNK + st * 16 + r16] = acc[lt][r];
  }
}

// ---------------- per (b,chunk,head): Y_diag + skip (bf16 out), chunk states ----------------
__global__ __launch_bounds__(256) void ssm_diag_kernel(
    const bf16* __restrict__ xg, const bf16* __restrict__ Bg,
    const float* __restrict__ CB, const float* __restrict__ dtv_buf,
    const float* __restrict__ dacs_buf, const float* __restrict__ Dskip,
    bf16* __restrict__ ybuf, float* __restrict__ states) {
  int blk = blockIdx.x;                        // (b*8+c)*64 + h
  int h = blk & 63, cc = (blk >> 6) & 7, b = blk >> 9;
  int tid = threadIdx.x, lane = tid & 63, w = tid >> 6, r16 = lane & 15, q = lane >> 4;

  __shared__ __align__(16) bf16 xT[HEADDIM][264];
  __shared__ __align__(16) bf16 Pl[CHUNK][32];
  __shared__ __align__(16) bf16 BwT[D_STATE][40];
  __shared__ __align__(16) float cs_s[CHUNK];
  __shared__ __align__(16) float dt_s[CHUNK];
  __shared__ __align__(16) float w_s[CHUNK];

  long hco = ((long)(b * NHEADS + h) * NC + cc) * CHUNK;
  cs_s[tid] = dacs_buf[hco + tid];
  dt_s[tid] = dtv_buf[hco + tid];
  __syncthreads();
  float cl_last = cs_s[CHUNK - 1];
  w_s[tid] = __expf(cl_last - cs_s[tid]) * dt_s[tid];

  const bf16* xbase = xg + ((long)b * SEQLEN + cc * CHUNK) * D_INNER + h * HEADDIM;
  for (int it = 0; it < 64; ++it) {
    int s = it * 4 + (tid >> 6);
    int p = tid & 63;
    xT[p][s] = xbase[(long)s * D_INNER + p];
  }
  __syncthreads();

  const float* CBchunk = CB + (long)(b * NC + cc) * CHUNK * CHUNK;
  const bf16* Bb = Bg + ((long)b * SEQLEN + cc * CHUNK) * D_STATE;
  f32x4v zero4 = {0.f, 0.f, 0.f, 0.f};
  f32x4v accY[4][4], accS[2][4];
#pragma unroll
  for (int i = 0; i < 4; ++i)
#pragma unroll
    for (int j = 0; j < 4; ++j) accY[i][j] = zero4;
#pragma unroll
  for (int i = 0; i < 2; ++i)
#pragma unroll
    for (int j = 0; j < 4; ++j) accS[i][j] = zero4;

  for (int ks = 0; ks < 8; ++ks) {
    __syncthreads();
    {
      int sj = tid & 31, g = tid >> 5;
      int s = ks * 32 + sj;
      float csv = cs_s[s], dts = dt_s[s];
      for (int i = 0; i < 32; ++i) {
        int l = g * 32 + i;
        float v = 0.f;
        if (s <= l) v = CBchunk[(long)l * CHUNK + s] * __expf(cs_s[l] - csv) * dts;
        Pl[l][sj] = f2b(v);
      }
    }
    for (int i2 = 0; i2 < 16; ++i2) {
      int idx = i2 * 256 + tid;
      int n = idx & 127, sj2 = idx >> 7;
      int s2 = ks * 32 + sj2;
      BwT[n][sj2] = f2b(b2f(Bb[(long)s2 * D_STATE + n]) * w_s[s2]);
    }
    __syncthreads();
    bfrag8 xf[4];
#pragma unroll
    for (int pt = 0; pt < 4; ++pt) xf[pt] = *(const bfrag8*)(&xT[pt * 16 + r16][ks * 32 + q * 8]);
#pragma unroll
    for (int lt = 0; lt < 4; ++lt) {
      bfrag8 pf = *(const bfrag8*)(&Pl[w * 64 + lt * 16 + r16][q * 8]);
#pragma unroll
      for (int pt = 0; pt < 4; ++pt) accY[lt][pt] = mfma16(pf, xf[pt], accY[lt][pt]);
    }
#pragma unroll
    for (int nt = 0; nt < 2; ++nt) {
      bfrag8 bwf = *(const bfrag8*)(&BwT[w * 32 + nt * 16 + r16][q * 8]);
#pragma unroll
      for (int pt = 0; pt < 4; ++pt) accS[nt][pt] = mfma16(bwf, xf[pt], accS[nt][pt]);
    }
  }

  float dsk = Dskip[h];
  bf16* ybase = ybuf + ((long)b * SEQLEN + cc * CHUNK) * D_INNER + h * HEADDIM;
#pragma unroll
  for (int lt = 0; lt < 4; ++lt)
#pragma unroll
    for (int pt = 0; pt < 4; ++pt)
#pragma unroll
      for (int r = 0; r < 4; ++r) {
        int lrow = w * 64 + lt * 16 + q * 4 + r;
        int pcol = pt * 16 + r16;
        ybase[(long)lrow * D_INNER + pcol] = f2b(accY[lt][pt][r] + b2f(xT[pcol][lrow]) * dsk);
      }
  float* sbase = states + (long)blk * (HEADDIM * D_STATE);
#pragma unroll
  for (int nt = 0; nt < 2; ++nt)
#pragma unroll
    for (int pt = 0; pt < 4; ++pt)
#pragma unroll
      for (int r = 0; r < 4; ++r)
        sbase[(long)(pt * 16 + r16) * D_STATE + w * 32 + nt * 16 + q * 4 + r] = accS[nt][pt][r];
}

// ---------------- inter-chunk state scan ----------------
__global__ __launch_bounds__(256) void state_scan_kernel(const float* __restrict__ states,
    const float* __restrict__ dacs, bf16* __restrict__ prevb) {
  int bh = blockIdx.x;                         // b*64 + h
  int h = bh & 63, b = bh >> 6;
  int tid = threadIdx.x;
  __shared__ __align__(16) float dec[NC];
  if (tid < NC)
    dec[tid] = __expf(dacs[((long)(b * NHEADS + h) * NC + tid) * CHUNK + (CHUNK - 1)]);
  __syncthreads();
  for (int i = 0; i < 32; ++i) {
    int e = i * 256 + tid;                     // p*128+n
    float carry = 0.f;
    for (int c = 0; c < NC; ++c) {
      long off = ((long)((b * NC + c) * NHEADS + h)) * (HEADDIM * D_STATE) + e;
      prevb[off] = f2b(carry);
      carry = carry * dec[c] + states[off];
    }
  }
}

// ---------------- Y_off = (C @ prev^T) * exp(cs[l]), bf16 RMW into ybuf ----------------
__global__ __launch_bounds__(256) void yoff_kernel(const bf16* __restrict__ Cg,
    const bf16* __restrict__ prevb, const float* __restrict__ dacs,
    bf16* __restrict__ ybuf) {
  int blk = blockIdx.x;                        // (b*8+c)*64 + h
  int h = blk & 63, cc = (blk >> 6) & 7, b = blk >> 9;
  int tid = threadIdx.x, lane = tid & 63, w = tid >> 6, r16 = lane & 15, q = lane >> 4;
  __shared__ __align__(16) float cs_s[CHUNK];
  cs_s[tid] = dacs[((long)(b * NHEADS + h) * NC + cc) * CHUNK + tid];
  __syncthreads();
  const bf16* Cb = Cg + ((long)b * SEQLEN + cc * CHUNK) * D_STATE;
  const bf16* Pb = prevb + (long)blk * (HEADDIM * D_STATE);
  f32x4v zero4 = {0.f, 0.f, 0.f, 0.f};
  f32x4v acc[4][4];
#pragma unroll
  for (int i = 0; i < 4; ++i)
#pragma unroll
    for (int j = 0; j < 4; ++j) acc[i][j] = zero4;
#pragma unroll
  for (int kk = 0; kk < 4; ++kk) {
    bfrag8 bv[4];
#pragma unroll
    for (int pt = 0; pt < 4; ++pt)
      bv[pt] = *(const bfrag8*)(Pb + (long)(pt * 16 + r16) * D_STATE + kk * 32 + q * 8);
#pragma unroll
    for (int lt = 0; lt < 4; ++lt) {
      bfrag8 av = *(const bfrag8*)(Cb + (long)(w * 64 + lt * 16 + r16) * D_STATE + kk * 32 + q * 8);
#pragma unroll
      for (int pt = 0; pt < 4; ++pt) acc[lt][pt] = mfma16(av, bv[pt], acc[lt][pt]);
    }
  }
  bf16* ybase = ybuf + ((long)b * SEQLEN + cc * CHUNK) * D_INNER + h * HEADDIM;
#pragma unroll
  for (int lt = 0; lt < 4; ++lt)
#pragma unroll
    for (int pt = 0; pt < 4; ++pt)
#pragma unroll
      for (int r = 0; r < 4; ++r) {
        int lrow = w * 64 + lt * 16 + q * 4 + r;
        float ef = __expf(cs_s[lrow]);
        bf16* p = ybase + (long)lrow * D_INNER + pt * 16 + r16;
        *p = f2b(b2f(*p) + acc[lt][pt][r] * ef);
      }
}

// ---------------- gate + RMSNorm, IN-PLACE on bf16 ybuf ----------------
__global__ __launch_bounds__(256) void gate_norm_kernel(bf16* __restrict__ ybuf,
    const bf16* __restrict__ zb, const float* __restrict__ norm_w) {
  int row = blockIdx.x, tid = threadIdx.x;
  bf16* y = ybuf + (long)row * D_INNER;
  const bf16* z = zb + (long)row * D_INNER;
  float v[16];
  float ss = 0.f;
#pragma unroll
  for (int i = 0; i < 2; ++i) {
    int e = tid * 16 + i * 8;
    bfrag8 yv = *(const bfrag8*)(y + e);
    bfrag8 zv = *(const bfrag8*)(z + e);
#pragma unroll
    for (int j = 0; j < 8; ++j) {
      float a = (float)yv[j] * siluf((float)zv[j]);
      v[i * 8 + j] = a;
      ss += a * a;
    }
  }
#pragma unroll
  for (int off = 32; off > 0; off >>= 1) ss += __shfl_down(ss, off);
  __shared__ __align__(16) float red[4];
  int lane = tid & 63, w = tid >> 6;
  if (lane == 0) red[w] = ss;
  __syncthreads();
  float tot = red[0] + red[1] + red[2] + red[3];
  float scale = rsqrtf(tot * (1.f / D_INNER) + RMS_EPS);
#pragma unroll
  for (int i = 0; i < 2; ++i) {
    int e = tid * 16 + i * 8;
    float4 w0 = *(const float4*)(norm_w + e);
    float4 w1 = *(const float4*)(norm_w + e + 4);
    bfrag8 o;
    o[0] = (__bf16)(v[i * 8 + 0] * scale * w0.x);
    o[1] = (__bf16)(v[i * 8 + 1] * scale * w0.y);
    o[2] = (__bf16)(v[i * 8 + 2] * scale * w0.z);
    o[3] = (__bf16)(v[i * 8 + 3] * scale * w0.w);
    o[4] = (__bf16)(v[i * 8 + 4] * scale * w1.x);
    o[5] = (__bf16)(v[i * 8 + 5] * scale * w1.y);
    o[6] = (__bf16)(v[i * 8 + 6] * scale * w1.z);
    o[7] = (__bf16)(v[i * 8 + 7] * scale * w1.w);
    *(bfrag8*)(y + e) = o;
  }
}

// ---------------- launch ----------------
extern "C" void kernel_launch(void* const* d_in, const int* in_sizes, int n_in,
                              void* d_out, int out_size, void* d_ws, size_t ws_size,
                              hipStream_t stream) {
  if (ws_size < WS_NEEDED) return;   // diagnostic: clean absmax fail if ws too small

  const float* u       = (const float*)d_in[0];
  const float* w_in    = (const float*)d_in[1];
  const float* conv_w  = (const float*)d_in[2];
  const float* conv_b  = (const float*)d_in[3];
  const float* dt_bias = (const float*)d_in[4];
  const float* A_log   = (const float*)d_in[5];
  const float* Dskip   = (const float*)d_in[6];
  const float* norm_w  = (const float*)d_in[7];
  const float* w_out   = (const float*)d_in[8];
  float* out = (float*)d_out;

  char* ws = (char*)d_ws;
  bf16*  win_bf  = (bf16*)(ws + OFF_WIN);
  bf16*  x_bf    = (bf16*)(ws + OFF_XBF);
  bf16*  prevb   = (bf16*)(ws + OFF_PREV);
  bf16*  wout_bf = (bf16*)(ws + OFF_WOUT);
  bf16*  u_bf    = (bf16*)(ws + OFF_UBF);
  float* dtv     = (float*)(ws + OFF_DTV);
  float* dacs    = (float*)(ws + OFF_DACS);
  bf16*  B_bf    = (bf16*)(ws + OFF_BBF);
  bf16*  C_bf    = (bf16*)(ws + OFF_CBF);
  float* CBb     = (float*)(ws + OFF_CB);
  bf16*  xbc_bf  = (bf16*)(ws + OFF_XBC);
  float* states  = (float*)(ws + OFF_STATE);
  bf16*  z_bf    = (bf16*)(ws + OFF_ZBF);
  float* dt_raw  = (float*)(ws + OFF_DTRAW);
  bf16*  ybuf    = (bf16*)(ws + OFF_YBUF);

  // 1-2. casts
  cast_kernel<<<8192, 256, 0, stream>>>(u, u_bf, (long)ROWSTOT * D_MODEL / 4);
  cast_pad_kernel<<<17152, 256, 0, stream>>>(w_in, win_bf);
  // 3. zxbcdt = u @ W_in^T, split epilogue
  gemm1_kernel<<<dim3(67, 32), 256, 0, stream>>>(u_bf, win_bf, z_bf, xbc_bf, dt_raw);
  // 4. dt softplus + per-chunk cumsum
  dt_scan_kernel<<<1024, 256, 0, stream>>>(dt_raw, dt_bias, A_log, dtv, dacs);
  // 5. conv1d + silu, split x/B/C
  conv_kernel<<<dim3(17, SEQLEN, 2), 256, 0, stream>>>(xbc_bf, conv_w, conv_b, x_bf, B_bf, C_bf);
  // 6. CB per (b,chunk)
  cb_kernel<<<16, 256, 0, stream>>>(C_bf, B_bf, CBb);
  // 7. Y_diag + skip + chunk states
  ssm_diag_kernel<<<1024, 256, 0, stream>>>(x_bf, B_bf, CBb, dtv, dacs, Dskip, ybuf, states);
  // 8. inter-chunk scan
  state_scan_kernel<<<128, 256, 0, stream>>>(states, dacs, prevb);
  // 9. Y_off accumulate
  yoff_kernel<<<1024, 256, 0, stream>>>(C_bf, prevb, dacs, ybuf);
  // 10. cast W_out
  cast_kernel<<<8192, 256, 0, stream>>>(w_out, wout_bf, (long)D_MODEL * D_INNER / 4);
  // 11. gate + RMSNorm (in-place on ybuf)
  gate_norm_kernel<<<ROWSTOT, 256, 0, stream>>>(ybuf, z_bf, norm_w);
  // 12. out = y @ W_out^T
  gemm2_kernel<<<dim3(16, 32), 256, 0, stream>>>(ybuf, wout_bf, out);
}

// Round 3
// 742.332 us; speedup vs baseline: 1.3477x; 1.3477x over previous
//
#include <hip/hip_runtime.h>
#include <hip/hip_bf16.h>

// Mamba2 layer, MI355X/gfx950. Round 2: ssm_diag restructured — no barriers in
// ks-loop, P/Bw frags built in registers (vectorized CB/BT global loads),
// LDS 62->37KB. conv now also emits global B^T for the bwf frags.

#define D_MODEL   2048
#define D_STATE   128
#define HEADDIM   64
#define CHUNK     256
#define D_INNER   4096
#define NHEADS    64
#define CONV_DIM  4352
#define D_IN_PROJ 8512
#define SEQLEN    2048
#define NC        8
#define ROWSTOT   4096
#define NPAD      8576
#define RMS_EPS   1e-5f

// ---- workspace layout (byte offsets), lifetime-overlaid ----
#define OFF_WIN   0ull
#define OFF_XBF   0ull
#define OFF_PREV  0ull
#define OFF_WOUT  16777216ull
#define OFF_UBF   35127296ull
#define OFF_DTV   35127296ull
#define OFF_DACS  36175872ull
#define OFF_BBF   37224448ull
#define OFF_CBF   38273024ull
#define OFF_CB    39321600ull
#define OFF_BT    43515904ull      // B^T[(b,c),n,s] bf16, 1MB (written step5, read step7)
#define OFF_XBC   51904512ull
#define OFF_STATE 51904512ull
#define OFF_ZBF   87556096ull
#define OFF_DTRAW 121110528ull
#define OFF_YBUF  121110528ull
#define WS_NEEDED 154664960ull

typedef __hip_bfloat16 bf16;
typedef __bf16 bfrag8 __attribute__((ext_vector_type(8)));
typedef float  f32x4v __attribute__((ext_vector_type(4)));

__device__ __forceinline__ f32x4v mfma16(bfrag8 a, bfrag8 b, f32x4v c) {
  return __builtin_amdgcn_mfma_f32_16x16x32_bf16(a, b, c, 0, 0, 0);
}

__device__ __forceinline__ void gload_lds16(const void* g, void* l) {
  __builtin_amdgcn_global_load_lds((const __attribute__((address_space(1))) void*)g,
                                   (__attribute__((address_space(3))) void*)l, 16, 0, 0);
}

__device__ __forceinline__ bf16 f2b(float x) { return __float2bfloat16(x); }
__device__ __forceinline__ float b2f(bf16 x) { return __bfloat162float(x); }
__device__ __forceinline__ float siluf(float x) { return x / (1.f + __expf(-x)); }

// ---------------- cast kernels ----------------
__global__ __launch_bounds__(256) void cast_kernel(const float* __restrict__ in,
                                                   bf16* __restrict__ out, long n4) {
  long i = (long)blockIdx.x * 256 + threadIdx.x;
  if (i >= n4) return;
  float4 v = ((const float4*)in)[i];
  bf16* o = out + i * 4;
  o[0] = f2b(v.x); o[1] = f2b(v.y); o[2] = f2b(v.z); o[3] = f2b(v.w);
}

__global__ __launch_bounds__(256) void cast_pad_kernel(const float* __restrict__ in,
                                                       bf16* __restrict__ out) {
  long i = (long)blockIdx.x * 256 + threadIdx.x;
  long e = i * 4;
  if (e >= (long)NPAD * D_MODEL) return;
  long row = e / D_MODEL;
  bf16* o = out + e;
  if (row < D_IN_PROJ) {
    float4 v = *(const float4*)(in + e);
    o[0] = f2b(v.x); o[1] = f2b(v.y); o[2] = f2b(v.z); o[3] = f2b(v.w);
  } else {
    bf16 z = f2b(0.f);
    o[0] = z; o[1] = z; o[2] = z; o[3] = z;
  }
}

// ---------------- GEMM1: zxbcdt, epilogue split into z / xBC / dt_raw ----------------
__global__ __launch_bounds__(256) void gemm1_kernel(const bf16* __restrict__ A,
                                                    const bf16* __restrict__ B,
                                                    bf16* __restrict__ zb,
                                                    bf16* __restrict__ xbc,
                                                    float* __restrict__ dtraw) {
  __shared__ __align__(16) bf16 As[128 * 32];
  __shared__ __align__(16) bf16 Bs[128 * 32];
  int tid = threadIdx.x, lane = tid & 63, w = tid >> 6;
  int wr = w >> 1, wc = w & 1, r16 = lane & 15, q = lane >> 4;
  long row0 = (long)blockIdx.y * 128, col0 = (long)blockIdx.x * 128;
  const int K = D_MODEL;
  f32x4v zero4 = {0.f, 0.f, 0.f, 0.f};
  f32x4v acc[4][4];
#pragma unroll
  for (int i = 0; i < 4; ++i)
#pragma unroll
    for (int j = 0; j < 4; ++j) acc[i][j] = zero4;

  for (int kt = 0; kt < K; kt += 32) {
    __syncthreads();
#pragma unroll
    for (int j = 0; j < 2; ++j) {
      int ci = (j * 4 + w) * 64 + lane;
      int r = ci >> 2, o8 = (ci & 3) * 8;
      gload_lds16(A + (row0 + r) * (long)K + kt + o8, (char*)As + (j * 4 + w) * 1024);
      gload_lds16(B + (col0 + r) * (long)K + kt + o8, (char*)Bs + (j * 4 + w) * 1024);
    }
    __syncthreads();
    bfrag8 af[4], bfv[4];
#pragma unroll
    for (int i = 0; i < 4; ++i) af[i]  = *(const bfrag8*)(As + (wr * 64 + i * 16 + r16) * 32 + q * 8);
#pragma unroll
    for (int i = 0; i < 4; ++i) bfv[i] = *(const bfrag8*)(Bs + (wc * 64 + i * 16 + r16) * 32 + q * 8);
#pragma unroll
    for (int i = 0; i < 4; ++i)
#pragma unroll
      for (int j = 0; j < 4; ++j) acc[i][j] = mfma16(af[i], bfv[j], acc[i][j]);
  }
#pragma unroll
  for (int i = 0; i < 4; ++i)
#pragma unroll
    for (int j = 0; j < 4; ++j) {
      long col = col0 + wc * 64 + j * 16 + r16;
#pragma unroll
      for (int r = 0; r < 4; ++r) {
        long row = row0 + wr * 64 + i * 16 + q * 4 + r;
        float v = acc[i][j][r];
        if (col < D_INNER)                       zb[row * D_INNER + col] = f2b(v);
        else if (col < D_INNER + CONV_DIM)       xbc[row * CONV_DIM + (col - D_INNER)] = f2b(v);
        else if (col < D_IN_PROJ)                dtraw[row * NHEADS + (col - D_INNER - CONV_DIM)] = v;
      }
    }
}

// ---------------- GEMM2 ----------------
__global__ __launch_bounds__(256) void gemm2_kernel(const bf16* __restrict__ A,
                                                    const bf16* __restrict__ B,
                                                    float* __restrict__ C) {
  __shared__ __align__(16) bf16 As[128 * 32];
  __shared__ __align__(16) bf16 Bs[128 * 32];
  int tid = threadIdx.x, lane = tid & 63, w = tid >> 6;
  int wr = w >> 1, wc = w & 1, r16 = lane & 15, q = lane >> 4;
  long row0 = (long)blockIdx.y * 128, col0 = (long)blockIdx.x * 128;
  const int K = D_INNER, ldc = D_MODEL;
  f32x4v zero4 = {0.f, 0.f, 0.f, 0.f};
  f32x4v acc[4][4];
#pragma unroll
  for (int i = 0; i < 4; ++i)
#pragma unroll
    for (int j = 0; j < 4; ++j) acc[i][j] = zero4;

  for (int kt = 0; kt < K; kt += 32) {
    __syncthreads();
#pragma unroll
    for (int j = 0; j < 2; ++j) {
      int ci = (j * 4 + w) * 64 + lane;
      int r = ci >> 2, o8 = (ci & 3) * 8;
      gload_lds16(A + (row0 + r) * (long)K + kt + o8, (char*)As + (j * 4 + w) * 1024);
      gload_lds16(B + (col0 + r) * (long)K + kt + o8, (char*)Bs + (j * 4 + w) * 1024);
    }
    __syncthreads();
    bfrag8 af[4], bfv[4];
#pragma unroll
    for (int i = 0; i < 4; ++i) af[i]  = *(const bfrag8*)(As + (wr * 64 + i * 16 + r16) * 32 + q * 8);
#pragma unroll
    for (int i = 0; i < 4; ++i) bfv[i] = *(const bfrag8*)(Bs + (wc * 64 + i * 16 + r16) * 32 + q * 8);
#pragma unroll
    for (int i = 0; i < 4; ++i)
#pragma unroll
      for (int j = 0; j < 4; ++j) acc[i][j] = mfma16(af[i], bfv[j], acc[i][j]);
  }
#pragma unroll
  for (int i = 0; i < 4; ++i)
#pragma unroll
    for (int j = 0; j < 4; ++j)
#pragma unroll
      for (int r = 0; r < 4; ++r) {
        long row = row0 + wr * 64 + i * 16 + q * 4 + r;
        long col = col0 + wc * 64 + j * 16 + r16;
        C[row * ldc + col] = acc[i][j][r];
      }
}

// ---------------- dt softplus + per-chunk cumsum ----------------
__global__ __launch_bounds__(256) void dt_scan_kernel(const float* __restrict__ dtraw,
    const float* __restrict__ dt_bias, const float* __restrict__ A_log,
    float* __restrict__ dtv_buf, float* __restrict__ dacs_buf) {
  int blk = blockIdx.x;
  int c = blk & 7, h = (blk >> 3) & 63, b = blk >> 9;
  int s = threadIdx.x;
  long row = (long)b * SEQLEN + c * CHUNK + s;
  float raw = dtraw[row * NHEADS + h] + dt_bias[h];
  float dtv = fmaxf(raw, 0.f) + log1pf(__expf(-fabsf(raw)));
  float A = -__expf(A_log[h]);
  __shared__ __align__(16) float sc[CHUNK];
  sc[s] = dtv * A;
  __syncthreads();
  for (int off = 1; off < CHUNK; off <<= 1) {
    float v = (s >= off) ? sc[s - off] : 0.f;
    __syncthreads();
    sc[s] += v;
    __syncthreads();
  }
  long o = ((long)(b * NHEADS + h) * NC + c) * CHUNK + s;
  dtv_buf[o] = dtv;
  dacs_buf[o] = sc[s];
}

// ---------------- conv1d + SiLU -> x / B / C, plus global B^T ----------------
__global__ __launch_bounds__(256) void conv_kernel(const bf16* __restrict__ xbc,
    const float* __restrict__ conv_w, const float* __restrict__ conv_b,
    bf16* __restrict__ xo, bf16* __restrict__ Bo, bf16* __restrict__ Co,
    bf16* __restrict__ BT) {
  int cidx = blockIdx.x * 256 + threadIdx.x;
  int l = blockIdx.y, b = blockIdx.z;
  float4 wv = *(const float4*)(conv_w + cidx * 4);
  float acc = conv_b[cidx];
  const bf16* base = xbc + (long)b * SEQLEN * CONV_DIM + cidx;
  float wk[4] = {wv.x, wv.y, wv.z, wv.w};
#pragma unroll
  for (int k = 0; k < 4; ++k) {
    int ls = l - 3 + k;
    if (ls >= 0) acc += wk[k] * b2f(base[(long)ls * CONV_DIM]);
  }
  bf16 o = f2b(siluf(acc));
  long rowo = (long)b * SEQLEN + l;
  if (cidx < D_INNER) {
    xo[rowo * D_INNER + cidx] = o;
  } else if (cidx < D_INNER + D_STATE) {
    int n = cidx - D_INNER;
    Bo[rowo * D_STATE + n] = o;
    int c = l >> 8, s = l & 255;
    BT[(((long)b * NC + c) * D_STATE + n) * CHUNK + s] = o;
  } else {
    Co[rowo * D_STATE + (cidx - D_INNER - D_STATE)] = o;
  }
}

// ---------------- CB[l,s] per (b,chunk) ----------------
__global__ __launch_bounds__(256) void cb_kernel(const bf16* __restrict__ Cg,
                                                 const bf16* __restrict__ Bg,
                                                 float* __restrict__ CB) {
  int blk = blockIdx.x;
  int c = blk & 7, b = blk >> 3;
  int tid = threadIdx.x, lane = tid & 63, w = tid >> 6, r16 = lane & 15, q = lane >> 4;
  const bf16* Cb = Cg + ((long)b * SEQLEN + c * CHUNK) * D_STATE;
  const bf16* Bb = Bg + ((long)b * SEQLEN + c * CHUNK) * D_STATE;
  bfrag8 af[4][4];
#pragma unroll
  for (int lt = 0; lt < 4; ++lt)
#pragma unroll
    for (int kk = 0; kk < 4; ++kk)
      af[lt][kk] = *(const bfrag8*)(Cb + (long)(w * 64 + lt * 16 + r16) * D_STATE + kk * 32 + q * 8);
  float* CBb = CB + (long)blk * CHUNK * CHUNK;
  f32x4v zero4 = {0.f, 0.f, 0.f, 0.f};
  for (int st = 0; st < 16; ++st) {
    f32x4v acc[4] = {zero4, zero4, zero4, zero4};
#pragma unroll
    for (int kk = 0; kk < 4; ++kk) {
      bfrag8 bfv = *(const bfrag8*)(Bb + (long)(st * 16 + r16) * D_STATE + kk * 32 + q * 8);
#pragma unroll
      for (int lt = 0; lt < 4; ++lt) acc[lt] = mfma16(af[lt][kk], bfv, acc[lt]);
    }
#pragma unroll
    for (int lt = 0; lt < 4; ++lt)
#pragma unroll
      for (int r = 0; r < 4; ++r)
        CBb[(long)(w * 64 + lt * 16 + q * 4 + r) * CHUNK + st * 16 + r16] = acc[lt][r];
  }
}

// ---------------- per (b,chunk,head): Y_diag + skip, chunk states ----------------
// Barrier-free K-loop: P and Bw fragments built in registers from global memory.
__global__ __launch_bounds__(256) void ssm_diag_kernel(
    const bf16* __restrict__ xg, const bf16* __restrict__ BT,
    const float* __restrict__ CB, const float* __restrict__ dtv_buf,
    const float* __restrict__ dacs_buf, const float* __restrict__ Dskip,
    bf16* __restrict__ ybuf, float* __restrict__ states) {
  int blk = blockIdx.x;                        // (b*8+c)*64 + h
  int h = blk & 63, cc = (blk >> 6) & 7, b = blk >> 9;
  int tid = threadIdx.x, lane = tid & 63, w = tid >> 6, r16 = lane & 15, q = lane >> 4;

  __shared__ __align__(16) __bf16 xT[HEADDIM][264];   // 33.8 KB, 16B-aligned rows
  __shared__ __align__(16) float cs_s[CHUNK];
  __shared__ __align__(16) float dt_s[CHUNK];
  __shared__ __align__(16) float w_s[CHUNK];

  long hco = ((long)(b * NHEADS + h) * NC + cc) * CHUNK;
  cs_s[tid] = dacs_buf[hco + tid];
  dt_s[tid] = dtv_buf[hco + tid];
  __syncthreads();
  float cl_last = cs_s[CHUNK - 1];
  w_s[tid] = __expf(cl_last - cs_s[tid]) * dt_s[tid];

  // stage x^T: 16B global loads, scalar LDS writes
  const __bf16* xbase = (const __bf16*)(xg + ((long)b * SEQLEN + cc * CHUNK) * D_INNER + h * HEADDIM);
#pragma unroll
  for (int it = 0; it < 8; ++it) {
    int e = it * 256 + tid;
    int s = e >> 3, p0 = (e & 7) * 8;
    bfrag8 xv = *(const bfrag8*)(xbase + (long)s * D_INNER + p0);
#pragma unroll
    for (int j = 0; j < 8; ++j) xT[p0 + j][s] = xv[j];
  }
  __syncthreads();

  const float* CBchunk = CB + (long)(b * NC + cc) * CHUNK * CHUNK;
  const __bf16* BTc = (const __bf16*)(BT + (((long)b * NC + cc) * D_STATE) * CHUNK);
  f32x4v zero4 = {0.f, 0.f, 0.f, 0.f};
  f32x4v accY[4][4], accS[2][4];
#pragma unroll
  for (int i = 0; i < 4; ++i)
#pragma unroll
    for (int j = 0; j < 4; ++j) accY[i][j] = zero4;
#pragma unroll
  for (int i = 0; i < 2; ++i)
#pragma unroll
    for (int j = 0; j < 4; ++j) accS[i][j] = zero4;

  int l_row[4];
  const float* CBrow[4];
#pragma unroll
  for (int lt = 0; lt < 4; ++lt) {
    l_row[lt] = w * 64 + lt * 16 + r16;
    CBrow[lt] = CBchunk + (long)l_row[lt] * CHUNK;
  }

#pragma unroll 2
  for (int ks = 0; ks < 8; ++ks) {
    int s0 = ks * 32 + q * 8;
    // shared-per-lane scalars for this k-slice
    float4 cs0 = *(const float4*)(cs_s + s0);
    float4 cs1 = *(const float4*)(cs_s + s0 + 4);
    float4 dt0 = *(const float4*)(dt_s + s0);
    float4 dt1 = *(const float4*)(dt_s + s0 + 4);
    float4 w0  = *(const float4*)(w_s + s0);
    float4 w1  = *(const float4*)(w_s + s0 + 4);
    float csv[8] = {cs0.x, cs0.y, cs0.z, cs0.w, cs1.x, cs1.y, cs1.z, cs1.w};
    float dtv8[8] = {dt0.x, dt0.y, dt0.z, dt0.w, dt1.x, dt1.y, dt1.z, dt1.w};
    float wv8[8]  = {w0.x, w0.y, w0.z, w0.w, w1.x, w1.y, w1.z, w1.w};

    // x fragments from LDS
    bfrag8 xf[4];
#pragma unroll
    for (int pt = 0; pt < 4; ++pt) xf[pt] = *(const bfrag8*)(&xT[pt * 16 + r16][s0]);

    // P fragments: registers from CB global
#pragma unroll
    for (int lt = 0; lt < 4; ++lt) {
      int l = l_row[lt];
      float cs_l = cs_s[l];
      float4 cb0 = *(const float4*)(CBrow[lt] + s0);
      float4 cb1 = *(const float4*)(CBrow[lt] + s0 + 4);
      float cbv[8] = {cb0.x, cb0.y, cb0.z, cb0.w, cb1.x, cb1.y, cb1.z, cb1.w};
      bfrag8 pf;
#pragma unroll
      for (int j = 0; j < 8; ++j) {
        float v = (s0 + j <= l)
                    ? cbv[j] * __expf(fminf(cs_l - csv[j], 0.f)) * dtv8[j]
                    : 0.f;
        pf[j] = (__bf16)v;
      }
#pragma unroll
      for (int pt = 0; pt < 4; ++pt) accY[lt][pt] = mfma16(pf, xf[pt], accY[lt][pt]);
    }

    // Bw fragments: registers from BT global, scaled by w_s
#pragma unroll
    for (int nt = 0; nt < 2; ++nt) {
      int n = w * 32 + nt * 16 + r16;
      bfrag8 braw = *(const bfrag8*)(BTc + (long)n * CHUNK + s0);
      bfrag8 bwf;
#pragma unroll
      for (int j = 0; j < 8; ++j) bwf[j] = (__bf16)((float)braw[j] * wv8[j]);
#pragma unroll
      for (int pt = 0; pt < 4; ++pt) accS[nt][pt] = mfma16(bwf, xf[pt], accS[nt][pt]);
    }
  }

  // epilogue
  float dsk = Dskip[h];
  bf16* ybase = ybuf + ((long)b * SEQLEN + cc * CHUNK) * D_INNER + h * HEADDIM;
#pragma unroll
  for (int lt = 0; lt < 4; ++lt)
#pragma unroll
    for (int pt = 0; pt < 4; ++pt)
#pragma unroll
      for (int r = 0; r < 4; ++r) {
        int lrow = w * 64 + lt * 16 + q * 4 + r;
        int pcol = pt * 16 + r16;
        ybase[(long)lrow * D_INNER + pcol] = f2b(accY[lt][pt][r] + (float)xT[pcol][lrow] * dsk);
      }
  float* sbase = states + (long)blk * (HEADDIM * D_STATE);
#pragma unroll
  for (int nt = 0; nt < 2; ++nt)
#pragma unroll
    for (int pt = 0; pt < 4; ++pt)
#pragma unroll
      for (int r = 0; r < 4; ++r)
        sbase[(long)(pt * 16 + r16) * D_STATE + w * 32 + nt * 16 + q * 4 + r] = accS[nt][pt][r];
}

// ---------------- inter-chunk state scan ----------------
__global__ __launch_bounds__(256) void state_scan_kernel(const float* __restrict__ states,
    const float* __restrict__ dacs, bf16* __restrict__ prevb) {
  int bh = blockIdx.x;
  int h = bh & 63, b = bh >> 6;
  int tid = threadIdx.x;
  __shared__ __align__(16) float dec[NC];
  if (tid < NC)
    dec[tid] = __expf(dacs[((long)(b * NHEADS + h) * NC + tid) * CHUNK + (CHUNK - 1)]);
  __syncthreads();
  for (int i = 0; i < 32; ++i) {
    int e = i * 256 + tid;
    float carry = 0.f;
    for (int c = 0; c < NC; ++c) {
      long off = ((long)((b * NC + c) * NHEADS + h)) * (HEADDIM * D_STATE) + e;
      prevb[off] = f2b(carry);
      carry = carry * dec[c] + states[off];
    }
  }
}

// ---------------- Y_off accumulate (bf16 RMW) ----------------
__global__ __launch_bounds__(256) void yoff_kernel(const bf16* __restrict__ Cg,
    const bf16* __restrict__ prevb, const float* __restrict__ dacs,
    bf16* __restrict__ ybuf) {
  int blk = blockIdx.x;
  int h = blk & 63, cc = (blk >> 6) & 7, b = blk >> 9;
  int tid = threadIdx.x, lane = tid & 63, w = tid >> 6, r16 = lane & 15, q = lane >> 4;
  __shared__ __align__(16) float cs_s[CHUNK];
  cs_s[tid] = dacs[((long)(b * NHEADS + h) * NC + cc) * CHUNK + tid];
  __syncthreads();
  const bf16* Cb = Cg + ((long)b * SEQLEN + cc * CHUNK) * D_STATE;
  const bf16* Pb = prevb + (long)blk * (HEADDIM * D_STATE);
  f32x4v zero4 = {0.f, 0.f, 0.f, 0.f};
  f32x4v acc[4][4];
#pragma unroll
  for (int i = 0; i < 4; ++i)
#pragma unroll
    for (int j = 0; j < 4; ++j) acc[i][j] = zero4;
#pragma unroll
  for (int kk = 0; kk < 4; ++kk) {
    bfrag8 bv[4];
#pragma unroll
    for (int pt = 0; pt < 4; ++pt)
      bv[pt] = *(const bfrag8*)(Pb + (long)(pt * 16 + r16) * D_STATE + kk * 32 + q * 8);
#pragma unroll
    for (int lt = 0; lt < 4; ++lt) {
      bfrag8 av = *(const bfrag8*)(Cb + (long)(w * 64 + lt * 16 + r16) * D_STATE + kk * 32 + q * 8);
#pragma unroll
      for (int pt = 0; pt < 4; ++pt) acc[lt][pt] = mfma16(av, bv[pt], acc[lt][pt]);
    }
  }
  bf16* ybase = ybuf + ((long)b * SEQLEN + cc * CHUNK) * D_INNER + h * HEADDIM;
#pragma unroll
  for (int lt = 0; lt < 4; ++lt)
#pragma unroll
    for (int pt = 0; pt < 4; ++pt)
#pragma unroll
      for (int r = 0; r < 4; ++r) {
        int lrow = w * 64 + lt * 16 + q * 4 + r;
        float ef = __expf(cs_s[lrow]);
        bf16* p = ybase + (long)lrow * D_INNER + pt * 16 + r16;
        *p = f2b(b2f(*p) + acc[lt][pt][r] * ef);
      }
}

// ---------------- gate + RMSNorm, in-place ----------------
__global__ __launch_bounds__(256) void gate_norm_kernel(bf16* __restrict__ ybuf,
    const bf16* __restrict__ zb, const float* __restrict__ norm_w) {
  int row = blockIdx.x, tid = threadIdx.x;
  bf16* y = ybuf + (long)row * D_INNER;
  const bf16* z = zb + (long)row * D_INNER;
  float v[16];
  float ss = 0.f;
#pragma unroll
  for (int i = 0; i < 2; ++i) {
    int e = tid * 16 + i * 8;
    bfrag8 yv = *(const bfrag8*)(y + e);
    bfrag8 zv = *(const bfrag8*)(z + e);
#pragma unroll
    for (int j = 0; j < 8; ++j) {
      float a = (float)yv[j] * siluf((float)zv[j]);
      v[i * 8 + j] = a;
      ss += a * a;
    }
  }
#pragma unroll
  for (int off = 32; off > 0; off >>= 1) ss += __shfl_down(ss, off);
  __shared__ __align__(16) float red[4];
  int lane = tid & 63, w = tid >> 6;
  if (lane == 0) red[w] = ss;
  __syncthreads();
  float tot = red[0] + red[1] + red[2] + red[3];
  float scale = rsqrtf(tot * (1.f / D_INNER) + RMS_EPS);
#pragma unroll
  for (int i = 0; i < 2; ++i) {
    int e = tid * 16 + i * 8;
    float4 w0 = *(const float4*)(norm_w + e);
    float4 w1 = *(const float4*)(norm_w + e + 4);
    bfrag8 o;
    o[0] = (__bf16)(v[i * 8 + 0] * scale * w0.x);
    o[1] = (__bf16)(v[i * 8 + 1] * scale * w0.y);
    o[2] = (__bf16)(v[i * 8 + 2] * scale * w0.z);
    o[3] = (__bf16)(v[i * 8 + 3] * scale * w0.w);
    o[4] = (__bf16)(v[i * 8 + 4] * scale * w1.x);
    o[5] = (__bf16)(v[i * 8 + 5] * scale * w1.y);
    o[6] = (__bf16)(v[i * 8 + 6] * scale * w1.z);
    o[7] = (__bf16)(v[i * 8 + 7] * scale * w1.w);
    *(bfrag8*)(y + e) = o;
  }
}

// ---------------- launch ----------------
extern "C" void kernel_launch(void* const* d_in, const int* in_sizes, int n_in,
                              void* d_out, int out_size, void* d_ws, size_t ws_size,
                              hipStream_t stream) {
  if (ws_size < WS_NEEDED) return;

  const float* u       = (const float*)d_in[0];
  const float* w_in    = (const float*)d_in[1];
  const float* conv_w  = (const float*)d_in[2];
  const float* conv_b  = (const float*)d_in[3];
  const float* dt_bias = (const float*)d_in[4];
  const float* A_log   = (const float*)d_in[5];
  const float* Dskip   = (const float*)d_in[6];
  const float* norm_w  = (const float*)d_in[7];
  const float* w_out   = (const float*)d_in[8];
  float* out = (float*)d_out;

  char* ws = (char*)d_ws;
  bf16*  win_bf  = (bf16*)(ws + OFF_WIN);
  bf16*  x_bf    = (bf16*)(ws + OFF_XBF);
  bf16*  prevb   = (bf16*)(ws + OFF_PREV);
  bf16*  wout_bf = (bf16*)(ws + OFF_WOUT);
  bf16*  u_bf    = (bf16*)(ws + OFF_UBF);
  float* dtv     = (float*)(ws + OFF_DTV);
  float* dacs    = (float*)(ws + OFF_DACS);
  bf16*  B_bf    = (bf16*)(ws + OFF_BBF);
  bf16*  C_bf    = (bf16*)(ws + OFF_CBF);
  float* CBb     = (float*)(ws + OFF_CB);
  bf16*  BT_bf   = (bf16*)(ws + OFF_BT);
  bf16*  xbc_bf  = (bf16*)(ws + OFF_XBC);
  float* states  = (float*)(ws + OFF_STATE);
  bf16*  z_bf    = (bf16*)(ws + OFF_ZBF);
  float* dt_raw  = (float*)(ws + OFF_DTRAW);
  bf16*  ybuf    = (bf16*)(ws + OFF_YBUF);

  cast_kernel<<<8192, 256, 0, stream>>>(u, u_bf, (long)ROWSTOT * D_MODEL / 4);
  cast_pad_kernel<<<17152, 256, 0, stream>>>(w_in, win_bf);
  gemm1_kernel<<<dim3(67, 32), 256, 0, stream>>>(u_bf, win_bf, z_bf, xbc_bf, dt_raw);
  dt_scan_kernel<<<1024, 256, 0, stream>>>(dt_raw, dt_bias, A_log, dtv, dacs);
  conv_kernel<<<dim3(17, SEQLEN, 2), 256, 0, stream>>>(xbc_bf, conv_w, conv_b, x_bf, B_bf, C_bf, BT_bf);
  cb_kernel<<<16, 256, 0, stream>>>(C_bf, B_bf, CBb);
  ssm_diag_kernel<<<1024, 256, 0, stream>>>(x_bf, BT_bf, CBb, dtv, dacs, Dskip, ybuf, states);
  state_scan_kernel<<<128, 256, 0, stream>>>(states, dacs, prevb);
  yoff_kernel<<<1024, 256, 0, stream>>>(C_bf, prevb, dacs, ybuf);
  cast_kernel<<<8192, 256, 0, stream>>>(w_out, wout_bf, (long)D_MODEL * D_INNER / 4);
  gate_norm_kernel<<<ROWSTOT, 256, 0, stream>>>(ybuf, z_bf, norm_w);
  gemm2_kernel<<<dim3(16, 32), 256, 0, stream>>>(ybuf, wout_bf, out);
}

// Round 4
// 724.722 us; speedup vs baseline: 1.3804x; 1.0243x over previous
//
#include <hip/hip_runtime.h>
#include <hip/hip_bf16.h>

// Mamba2 layer, MI355X/gfx950. Round 3: supertile block swizzle in both GEMMs
// (grouped tile order -> L2 slab reuse; FETCH_SIZE was 12x over ideal).

#define D_MODEL   2048
#define D_STATE   128
#define HEADDIM   64
#define CHUNK     256
#define D_INNER   4096
#define NHEADS    64
#define CONV_DIM  4352
#define D_IN_PROJ 8512
#define SEQLEN    2048
#define NC        8
#define ROWSTOT   4096
#define NPAD      8576
#define RMS_EPS   1e-5f

// ---- workspace layout (byte offsets), lifetime-overlaid ----
#define OFF_WIN   0ull
#define OFF_XBF   0ull
#define OFF_PREV  0ull
#define OFF_WOUT  16777216ull
#define OFF_UBF   35127296ull
#define OFF_DTV   35127296ull
#define OFF_DACS  36175872ull
#define OFF_BBF   37224448ull
#define OFF_CBF   38273024ull
#define OFF_CB    39321600ull
#define OFF_BT    43515904ull
#define OFF_XBC   51904512ull
#define OFF_STATE 51904512ull
#define OFF_ZBF   87556096ull
#define OFF_DTRAW 121110528ull
#define OFF_YBUF  121110528ull
#define WS_NEEDED 154664960ull

typedef __hip_bfloat16 bf16;
typedef __bf16 bfrag8 __attribute__((ext_vector_type(8)));
typedef float  f32x4v __attribute__((ext_vector_type(4)));

__device__ __forceinline__ f32x4v mfma16(bfrag8 a, bfrag8 b, f32x4v c) {
  return __builtin_amdgcn_mfma_f32_16x16x32_bf16(a, b, c, 0, 0, 0);
}

__device__ __forceinline__ void gload_lds16(const void* g, void* l) {
  __builtin_amdgcn_global_load_lds((const __attribute__((address_space(1))) void*)g,
                                   (__attribute__((address_space(3))) void*)l, 16, 0, 0);
}

__device__ __forceinline__ bf16 f2b(float x) { return __float2bfloat16(x); }
__device__ __forceinline__ float b2f(bf16 x) { return __bfloat162float(x); }
__device__ __forceinline__ float siluf(float x) { return x / (1.f + __expf(-x)); }

// ---------------- cast kernels ----------------
__global__ __launch_bounds__(256) void cast_kernel(const float* __restrict__ in,
                                                   bf16* __restrict__ out, long n4) {
  long i = (long)blockIdx.x * 256 + threadIdx.x;
  if (i >= n4) return;
  float4 v = ((const float4*)in)[i];
  bf16* o = out + i * 4;
  o[0] = f2b(v.x); o[1] = f2b(v.y); o[2] = f2b(v.z); o[3] = f2b(v.w);
}

__global__ __launch_bounds__(256) void cast_pad_kernel(const float* __restrict__ in,
                                                       bf16* __restrict__ out) {
  long i = (long)blockIdx.x * 256 + threadIdx.x;
  long e = i * 4;
  if (e >= (long)NPAD * D_MODEL) return;
  long row = e / D_MODEL;
  bf16* o = out + e;
  if (row < D_IN_PROJ) {
    float4 v = *(const float4*)(in + e);
    o[0] = f2b(v.x); o[1] = f2b(v.y); o[2] = f2b(v.z); o[3] = f2b(v.w);
  } else {
    bf16 z = f2b(0.f);
    o[0] = z; o[1] = z; o[2] = z; o[3] = z;
  }
}

// ---------------- GEMM1: zxbcdt, split epilogue; supertile-swizzled 1D grid ----
// tiles: 32 (M) x 67 (N). Supertile = 16x8 tiles = 128 blocks; super grid 2x9
// (N padded to 72 tiles, tn>=67 returns). Contiguous pids share 16 A-slabs +
// 8 B-slabs = 12 MB -> L2-resident.
__global__ __launch_bounds__(256) void gemm1_kernel(const bf16* __restrict__ A,
                                                    const bf16* __restrict__ B,
                                                    bf16* __restrict__ zb,
                                                    bf16* __restrict__ xbc,
                                                    float* __restrict__ dtraw) {
  int pid = blockIdx.x;
  int t = pid & 127, s = pid >> 7;
  int sm = s / 9, sn = s % 9;
  int tm = sm * 16 + (t & 15);
  int tn = sn * 8 + (t >> 4);
  if (tn >= 67) return;
  long row0 = (long)tm * 128, col0 = (long)tn * 128;

  __shared__ __align__(16) bf16 As[128 * 32];
  __shared__ __align__(16) bf16 Bs[128 * 32];
  int tid = threadIdx.x, lane = tid & 63, w = tid >> 6;
  int wr = w >> 1, wc = w & 1, r16 = lane & 15, q = lane >> 4;
  const int K = D_MODEL;
  f32x4v zero4 = {0.f, 0.f, 0.f, 0.f};
  f32x4v acc[4][4];
#pragma unroll
  for (int i = 0; i < 4; ++i)
#pragma unroll
    for (int j = 0; j < 4; ++j) acc[i][j] = zero4;

  for (int kt = 0; kt < K; kt += 32) {
    __syncthreads();
#pragma unroll
    for (int j = 0; j < 2; ++j) {
      int ci = (j * 4 + w) * 64 + lane;
      int r = ci >> 2, o8 = (ci & 3) * 8;
      gload_lds16(A + (row0 + r) * (long)K + kt + o8, (char*)As + (j * 4 + w) * 1024);
      gload_lds16(B + (col0 + r) * (long)K + kt + o8, (char*)Bs + (j * 4 + w) * 1024);
    }
    __syncthreads();
    bfrag8 af[4], bfv[4];
#pragma unroll
    for (int i = 0; i < 4; ++i) af[i]  = *(const bfrag8*)(As + (wr * 64 + i * 16 + r16) * 32 + q * 8);
#pragma unroll
    for (int i = 0; i < 4; ++i) bfv[i] = *(const bfrag8*)(Bs + (wc * 64 + i * 16 + r16) * 32 + q * 8);
#pragma unroll
    for (int i = 0; i < 4; ++i)
#pragma unroll
      for (int j = 0; j < 4; ++j) acc[i][j] = mfma16(af[i], bfv[j], acc[i][j]);
  }
#pragma unroll
  for (int i = 0; i < 4; ++i)
#pragma unroll
    for (int j = 0; j < 4; ++j) {
      long col = col0 + wc * 64 + j * 16 + r16;
#pragma unroll
      for (int r = 0; r < 4; ++r) {
        long row = row0 + wr * 64 + i * 16 + q * 4 + r;
        float v = acc[i][j][r];
        if (col < D_INNER)                       zb[row * D_INNER + col] = f2b(v);
        else if (col < D_INNER + CONV_DIM)       xbc[row * CONV_DIM + (col - D_INNER)] = f2b(v);
        else if (col < D_IN_PROJ)                dtraw[row * NHEADS + (col - D_INNER - CONV_DIM)] = v;
      }
    }
}

// ---------------- GEMM2: supertile-swizzled (tiles 32x16, supertile 8x8) ----
__global__ __launch_bounds__(256) void gemm2_kernel(const bf16* __restrict__ A,
                                                    const bf16* __restrict__ B,
                                                    float* __restrict__ C) {
  int pid = blockIdx.x;
  int t = pid & 63, s = pid >> 6;         // 8 supertiles: 4 (M) x 2 (N)
  int sm = s >> 1, sn = s & 1;
  int tm = sm * 8 + (t & 7);
  int tn = sn * 8 + (t >> 3);
  long row0 = (long)tm * 128, col0 = (long)tn * 128;

  __shared__ __align__(16) bf16 As[128 * 32];
  __shared__ __align__(16) bf16 Bs[128 * 32];
  int tid = threadIdx.x, lane = tid & 63, w = tid >> 6;
  int wr = w >> 1, wc = w & 1, r16 = lane & 15, q = lane >> 4;
  const int K = D_INNER, ldc = D_MODEL;
  f32x4v zero4 = {0.f, 0.f, 0.f, 0.f};
  f32x4v acc[4][4];
#pragma unroll
  for (int i = 0; i < 4; ++i)
#pragma unroll
    for (int j = 0; j < 4; ++j) acc[i][j] = zero4;

  for (int kt = 0; kt < K; kt += 32) {
    __syncthreads();
#pragma unroll
    for (int j = 0; j < 2; ++j) {
      int ci = (j * 4 + w) * 64 + lane;
      int r = ci >> 2, o8 = (ci & 3) * 8;
      gload_lds16(A + (row0 + r) * (long)K + kt + o8, (char*)As + (j * 4 + w) * 1024);
      gload_lds16(B + (col0 + r) * (long)K + kt + o8, (char*)Bs + (j * 4 + w) * 1024);
    }
    __syncthreads();
    bfrag8 af[4], bfv[4];
#pragma unroll
    for (int i = 0; i < 4; ++i) af[i]  = *(const bfrag8*)(As + (wr * 64 + i * 16 + r16) * 32 + q * 8);
#pragma unroll
    for (int i = 0; i < 4; ++i) bfv[i] = *(const bfrag8*)(Bs + (wc * 64 + i * 16 + r16) * 32 + q * 8);
#pragma unroll
    for (int i = 0; i < 4; ++i)
#pragma unroll
      for (int j = 0; j < 4; ++j) acc[i][j] = mfma16(af[i], bfv[j], acc[i][j]);
  }
#pragma unroll
  for (int i = 0; i < 4; ++i)
#pragma unroll
    for (int j = 0; j < 4; ++j)
#pragma unroll
      for (int r = 0; r < 4; ++r) {
        long row = row0 + wr * 64 + i * 16 + q * 4 + r;
        long col = col0 + wc * 64 + j * 16 + r16;
        C[row * ldc + col] = acc[i][j][r];
      }
}

// ---------------- dt softplus + per-chunk cumsum ----------------
__global__ __launch_bounds__(256) void dt_scan_kernel(const float* __restrict__ dtraw,
    const float* __restrict__ dt_bias, const float* __restrict__ A_log,
    float* __restrict__ dtv_buf, float* __restrict__ dacs_buf) {
  int blk = blockIdx.x;
  int c = blk & 7, h = (blk >> 3) & 63, b = blk >> 9;
  int s = threadIdx.x;
  long row = (long)b * SEQLEN + c * CHUNK + s;
  float raw = dtraw[row * NHEADS + h] + dt_bias[h];
  float dtv = fmaxf(raw, 0.f) + log1pf(__expf(-fabsf(raw)));
  float A = -__expf(A_log[h]);
  __shared__ __align__(16) float sc[CHUNK];
  sc[s] = dtv * A;
  __syncthreads();
  for (int off = 1; off < CHUNK; off <<= 1) {
    float v = (s >= off) ? sc[s - off] : 0.f;
    __syncthreads();
    sc[s] += v;
    __syncthreads();
  }
  long o = ((long)(b * NHEADS + h) * NC + c) * CHUNK + s;
  dtv_buf[o] = dtv;
  dacs_buf[o] = sc[s];
}

// ---------------- conv1d + SiLU -> x / B / C, plus global B^T ----------------
__global__ __launch_bounds__(256) void conv_kernel(const bf16* __restrict__ xbc,
    const float* __restrict__ conv_w, const float* __restrict__ conv_b,
    bf16* __restrict__ xo, bf16* __restrict__ Bo, bf16* __restrict__ Co,
    bf16* __restrict__ BT) {
  int cidx = blockIdx.x * 256 + threadIdx.x;
  int l = blockIdx.y, b = blockIdx.z;
  float4 wv = *(const float4*)(conv_w + cidx * 4);
  float acc = conv_b[cidx];
  const bf16* base = xbc + (long)b * SEQLEN * CONV_DIM + cidx;
  float wk[4] = {wv.x, wv.y, wv.z, wv.w};
#pragma unroll
  for (int k = 0; k < 4; ++k) {
    int ls = l - 3 + k;
    if (ls >= 0) acc += wk[k] * b2f(base[(long)ls * CONV_DIM]);
  }
  bf16 o = f2b(siluf(acc));
  long rowo = (long)b * SEQLEN + l;
  if (cidx < D_INNER) {
    xo[rowo * D_INNER + cidx] = o;
  } else if (cidx < D_INNER + D_STATE) {
    int n = cidx - D_INNER;
    Bo[rowo * D_STATE + n] = o;
    int c = l >> 8, s = l & 255;
    BT[(((long)b * NC + c) * D_STATE + n) * CHUNK + s] = o;
  } else {
    Co[rowo * D_STATE + (cidx - D_INNER - D_STATE)] = o;
  }
}

// ---------------- CB[l,s] per (b,chunk) ----------------
__global__ __launch_bounds__(256) void cb_kernel(const bf16* __restrict__ Cg,
                                                 const bf16* __restrict__ Bg,
                                                 float* __restrict__ CB) {
  int blk = blockIdx.x;
  int c = blk & 7, b = blk >> 3;
  int tid = threadIdx.x, lane = tid & 63, w = tid >> 6, r16 = lane & 15, q = lane >> 4;
  const bf16* Cb = Cg + ((long)b * SEQLEN + c * CHUNK) * D_STATE;
  const bf16* Bb = Bg + ((long)b * SEQLEN + c * CHUNK) * D_STATE;
  bfrag8 af[4][4];
#pragma unroll
  for (int lt = 0; lt < 4; ++lt)
#pragma unroll
    for (int kk = 0; kk < 4; ++kk)
      af[lt][kk] = *(const bfrag8*)(Cb + (long)(w * 64 + lt * 16 + r16) * D_STATE + kk * 32 + q * 8);
  float* CBb = CB + (long)blk * CHUNK * CHUNK;
  f32x4v zero4 = {0.f, 0.f, 0.f, 0.f};
  for (int st = 0; st < 16; ++st) {
    f32x4v acc[4] = {zero4, zero4, zero4, zero4};
#pragma unroll
    for (int kk = 0; kk < 4; ++kk) {
      bfrag8 bfv = *(const bfrag8*)(Bb + (long)(st * 16 + r16) * D_STATE + kk * 32 + q * 8);
#pragma unroll
      for (int lt = 0; lt < 4; ++lt) acc[lt] = mfma16(af[lt][kk], bfv, acc[lt]);
    }
#pragma unroll
    for (int lt = 0; lt < 4; ++lt)
#pragma unroll
      for (int r = 0; r < 4; ++r)
        CBb[(long)(w * 64 + lt * 16 + q * 4 + r) * CHUNK + st * 16 + r16] = acc[lt][r];
  }
}

// ---------------- per (b,chunk,head): Y_diag + skip, chunk states ----------------
__global__ __launch_bounds__(256) void ssm_diag_kernel(
    const bf16* __restrict__ xg, const bf16* __restrict__ BT,
    const float* __restrict__ CB, const float* __restrict__ dtv_buf,
    const float* __restrict__ dacs_buf, const float* __restrict__ Dskip,
    bf16* __restrict__ ybuf, float* __restrict__ states) {
  int blk = blockIdx.x;
  int h = blk & 63, cc = (blk >> 6) & 7, b = blk >> 9;
  int tid = threadIdx.x, lane = tid & 63, w = tid >> 6, r16 = lane & 15, q = lane >> 4;

  __shared__ __align__(16) __bf16 xT[HEADDIM][264];
  __shared__ __align__(16) float cs_s[CHUNK];
  __shared__ __align__(16) float dt_s[CHUNK];
  __shared__ __align__(16) float w_s[CHUNK];

  long hco = ((long)(b * NHEADS + h) * NC + cc) * CHUNK;
  cs_s[tid] = dacs_buf[hco + tid];
  dt_s[tid] = dtv_buf[hco + tid];
  __syncthreads();
  float cl_last = cs_s[CHUNK - 1];
  w_s[tid] = __expf(cl_last - cs_s[tid]) * dt_s[tid];

  const __bf16* xbase = (const __bf16*)(xg + ((long)b * SEQLEN + cc * CHUNK) * D_INNER + h * HEADDIM);
#pragma unroll
  for (int it = 0; it < 8; ++it) {
    int e = it * 256 + tid;
    int s = e >> 3, p0 = (e & 7) * 8;
    bfrag8 xv = *(const bfrag8*)(xbase + (long)s * D_INNER + p0);
#pragma unroll
    for (int j = 0; j < 8; ++j) xT[p0 + j][s] = xv[j];
  }
  __syncthreads();

  const float* CBchunk = CB + (long)(b * NC + cc) * CHUNK * CHUNK;
  const __bf16* BTc = (const __bf16*)(BT + (((long)b * NC + cc) * D_STATE) * CHUNK);
  f32x4v zero4 = {0.f, 0.f, 0.f, 0.f};
  f32x4v accY[4][4], accS[2][4];
#pragma unroll
  for (int i = 0; i < 4; ++i)
#pragma unroll
    for (int j = 0; j < 4; ++j) accY[i][j] = zero4;
#pragma unroll
  for (int i = 0; i < 2; ++i)
#pragma unroll
    for (int j = 0; j < 4; ++j) accS[i][j] = zero4;

  int l_row[4];
  const float* CBrow[4];
#pragma unroll
  for (int lt = 0; lt < 4; ++lt) {
    l_row[lt] = w * 64 + lt * 16 + r16;
    CBrow[lt] = CBchunk + (long)l_row[lt] * CHUNK;
  }

#pragma unroll 2
  for (int ks = 0; ks < 8; ++ks) {
    int s0 = ks * 32 + q * 8;
    float4 cs0 = *(const float4*)(cs_s + s0);
    float4 cs1 = *(const float4*)(cs_s + s0 + 4);
    float4 dt0 = *(const float4*)(dt_s + s0);
    float4 dt1 = *(const float4*)(dt_s + s0 + 4);
    float4 w0  = *(const float4*)(w_s + s0);
    float4 w1  = *(const float4*)(w_s + s0 + 4);
    float csv[8] = {cs0.x, cs0.y, cs0.z, cs0.w, cs1.x, cs1.y, cs1.z, cs1.w};
    float dtv8[8] = {dt0.x, dt0.y, dt0.z, dt0.w, dt1.x, dt1.y, dt1.z, dt1.w};
    float wv8[8]  = {w0.x, w0.y, w0.z, w0.w, w1.x, w1.y, w1.z, w1.w};

    bfrag8 xf[4];
#pragma unroll
    for (int pt = 0; pt < 4; ++pt) xf[pt] = *(const bfrag8*)(&xT[pt * 16 + r16][s0]);

#pragma unroll
    for (int lt = 0; lt < 4; ++lt) {
      int l = l_row[lt];
      float cs_l = cs_s[l];
      float4 cb0 = *(const float4*)(CBrow[lt] + s0);
      float4 cb1 = *(const float4*)(CBrow[lt] + s0 + 4);
      float cbv[8] = {cb0.x, cb0.y, cb0.z, cb0.w, cb1.x, cb1.y, cb1.z, cb1.w};
      bfrag8 pf;
#pragma unroll
      for (int j = 0; j < 8; ++j) {
        float v = (s0 + j <= l)
                    ? cbv[j] * __expf(fminf(cs_l - csv[j], 0.f)) * dtv8[j]
                    : 0.f;
        pf[j] = (__bf16)v;
      }
#pragma unroll
      for (int pt = 0; pt < 4; ++pt) accY[lt][pt] = mfma16(pf, xf[pt], accY[lt][pt]);
    }

#pragma unroll
    for (int nt = 0; nt < 2; ++nt) {
      int n = w * 32 + nt * 16 + r16;
      bfrag8 braw = *(const bfrag8*)(BTc + (long)n * CHUNK + s0);
      bfrag8 bwf;
#pragma unroll
      for (int j = 0; j < 8; ++j) bwf[j] = (__bf16)((float)braw[j] * wv8[j]);
#pragma unroll
      for (int pt = 0; pt < 4; ++pt) accS[nt][pt] = mfma16(bwf, xf[pt], accS[nt][pt]);
    }
  }

  float dsk = Dskip[h];
  bf16* ybase = ybuf + ((long)b * SEQLEN + cc * CHUNK) * D_INNER + h * HEADDIM;
#pragma unroll
  for (int lt = 0; lt < 4; ++lt)
#pragma unroll
    for (int pt = 0; pt < 4; ++pt)
#pragma unroll
      for (int r = 0; r < 4; ++r) {
        int lrow = w * 64 + lt * 16 + q * 4 + r;
        int pcol = pt * 16 + r16;
        ybase[(long)lrow * D_INNER + pcol] = f2b(accY[lt][pt][r] + (float)xT[pcol][lrow] * dsk);
      }
  float* sbase = states + (long)blk * (HEADDIM * D_STATE);
#pragma unroll
  for (int nt = 0; nt < 2; ++nt)
#pragma unroll
    for (int pt = 0; pt < 4; ++pt)
#pragma unroll
      for (int r = 0; r < 4; ++r)
        sbase[(long)(pt * 16 + r16) * D_STATE + w * 32 + nt * 16 + q * 4 + r] = accS[nt][pt][r];
}

// ---------------- inter-chunk state scan ----------------
__global__ __launch_bounds__(256) void state_scan_kernel(const float* __restrict__ states,
    const float* __restrict__ dacs, bf16* __restrict__ prevb) {
  int bh = blockIdx.x;
  int h = bh & 63, b = bh >> 6;
  int tid = threadIdx.x;
  __shared__ __align__(16) float dec[NC];
  if (tid < NC)
    dec[tid] = __expf(dacs[((long)(b * NHEADS + h) * NC + tid) * CHUNK + (CHUNK - 1)]);
  __syncthreads();
  for (int i = 0; i < 32; ++i) {
    int e = i * 256 + tid;
    float carry = 0.f;
    for (int c = 0; c < NC; ++c) {
      long off = ((long)((b * NC + c) * NHEADS + h)) * (HEADDIM * D_STATE) + e;
      prevb[off] = f2b(carry);
      carry = carry * dec[c] + states[off];
    }
  }
}

// ---------------- Y_off accumulate (bf16 RMW) ----------------
__global__ __launch_bounds__(256) void yoff_kernel(const bf16* __restrict__ Cg,
    const bf16* __restrict__ prevb, const float* __restrict__ dacs,
    bf16* __restrict__ ybuf) {
  int blk = blockIdx.x;
  int h = blk & 63, cc = (blk >> 6) & 7, b = blk >> 9;
  int tid = threadIdx.x, lane = tid & 63, w = tid >> 6, r16 = lane & 15, q = lane >> 4;
  __shared__ __align__(16) float cs_s[CHUNK];
  cs_s[tid] = dacs[((long)(b * NHEADS + h) * NC + cc) * CHUNK + tid];
  __syncthreads();
  const bf16* Cb = Cg + ((long)b * SEQLEN + cc * CHUNK) * D_STATE;
  const bf16* Pb = prevb + (long)blk * (HEADDIM * D_STATE);
  f32x4v zero4 = {0.f, 0.f, 0.f, 0.f};
  f32x4v acc[4][4];
#pragma unroll
  for (int i = 0; i < 4; ++i)
#pragma unroll
    for (int j = 0; j < 4; ++j) acc[i][j] = zero4;
#pragma unroll
  for (int kk = 0; kk < 4; ++kk) {
    bfrag8 bv[4];
#pragma unroll
    for (int pt = 0; pt < 4; ++pt)
      bv[pt] = *(const bfrag8*)(Pb + (long)(pt * 16 + r16) * D_STATE + kk * 32 + q * 8);
#pragma unroll
    for (int lt = 0; lt < 4; ++lt) {
      bfrag8 av = *(const bfrag8*)(Cb + (long)(w * 64 + lt * 16 + r16) * D_STATE + kk * 32 + q * 8);
#pragma unroll
      for (int pt = 0; pt < 4; ++pt) acc[lt][pt] = mfma16(av, bv[pt], acc[lt][pt]);
    }
  }
  bf16* ybase = ybuf + ((long)b * SEQLEN + cc * CHUNK) * D_INNER + h * HEADDIM;
#pragma unroll
  for (int lt = 0; lt < 4; ++lt)
#pragma unroll
    for (int pt = 0; pt < 4; ++pt)
#pragma unroll
      for (int r = 0; r < 4; ++r) {
        int lrow = w * 64 + lt * 16 + q * 4 + r;
        float ef = __expf(cs_s[lrow]);
        bf16* p = ybase + (long)lrow * D_INNER + pt * 16 + r16;
        *p = f2b(b2f(*p) + acc[lt][pt][r] * ef);
      }
}

// ---------------- gate + RMSNorm, in-place ----------------
__global__ __launch_bounds__(256) void gate_norm_kernel(bf16* __restrict__ ybuf,
    const bf16* __restrict__ zb, const float* __restrict__ norm_w) {
  int row = blockIdx.x, tid = threadIdx.x;
  bf16* y = ybuf + (long)row * D_INNER;
  const bf16* z = zb + (long)row * D_INNER;
  float v[16];
  float ss = 0.f;
#pragma unroll
  for (int i = 0; i < 2; ++i) {
    int e = tid * 16 + i * 8;
    bfrag8 yv = *(const bfrag8*)(y + e);
    bfrag8 zv = *(const bfrag8*)(z + e);
#pragma unroll
    for (int j = 0; j < 8; ++j) {
      float a = (float)yv[j] * siluf((float)zv[j]);
      v[i * 8 + j] = a;
      ss += a * a;
    }
  }
#pragma unroll
  for (int off = 32; off > 0; off >>= 1) ss += __shfl_down(ss, off);
  __shared__ __align__(16) float red[4];
  int lane = tid & 63, w = tid >> 6;
  if (lane == 0) red[w] = ss;
  __syncthreads();
  float tot = red[0] + red[1] + red[2] + red[3];
  float scale = rsqrtf(tot * (1.f / D_INNER) + RMS_EPS);
#pragma unroll
  for (int i = 0; i < 2; ++i) {
    int e = tid * 16 + i * 8;
    float4 w0 = *(const float4*)(norm_w + e);
    float4 w1 = *(const float4*)(norm_w + e + 4);
    bfrag8 o;
    o[0] = (__bf16)(v[i * 8 + 0] * scale * w0.x);
    o[1] = (__bf16)(v[i * 8 + 1] * scale * w0.y);
    o[2] = (__bf16)(v[i * 8 + 2] * scale * w0.z);
    o[3] = (__bf16)(v[i * 8 + 3] * scale * w0.w);
    o[4] = (__bf16)(v[i * 8 + 4] * scale * w1.x);
    o[5] = (__bf16)(v[i * 8 + 5] * scale * w1.y);
    o[6] = (__bf16)(v[i * 8 + 6] * scale * w1.z);
    o[7] = (__bf16)(v[i * 8 + 7] * scale * w1.w);
    *(bfrag8*)(y + e) = o;
  }
}

// ---------------- launch ----------------
extern "C" void kernel_launch(void* const* d_in, const int* in_sizes, int n_in,
                              void* d_out, int out_size, void* d_ws, size_t ws_size,
                              hipStream_t stream) {
  if (ws_size < WS_NEEDED) return;

  const float* u       = (const float*)d_in[0];
  const float* w_in    = (const float*)d_in[1];
  const float* conv_w  = (const float*)d_in[2];
  const float* conv_b  = (const float*)d_in[3];
  const float* dt_bias = (const float*)d_in[4];
  const float* A_log   = (const float*)d_in[5];
  const float* Dskip   = (const float*)d_in[6];
  const float* norm_w  = (const float*)d_in[7];
  const float* w_out   = (const float*)d_in[8];
  float* out = (float*)d_out;

  char* ws = (char*)d_ws;
  bf16*  win_bf  = (bf16*)(ws + OFF_WIN);
  bf16*  x_bf    = (bf16*)(ws + OFF_XBF);
  bf16*  prevb   = (bf16*)(ws + OFF_PREV);
  bf16*  wout_bf = (bf16*)(ws + OFF_WOUT);
  bf16*  u_bf    = (bf16*)(ws + OFF_UBF);
  float* dtv     = (float*)(ws + OFF_DTV);
  float* dacs    = (float*)(ws + OFF_DACS);
  bf16*  B_bf    = (bf16*)(ws + OFF_BBF);
  bf16*  C_bf    = (bf16*)(ws + OFF_CBF);
  float* CBb     = (float*)(ws + OFF_CB);
  bf16*  BT_bf   = (bf16*)(ws + OFF_BT);
  bf16*  xbc_bf  = (bf16*)(ws + OFF_XBC);
  float* states  = (float*)(ws + OFF_STATE);
  bf16*  z_bf    = (bf16*)(ws + OFF_ZBF);
  float* dt_raw  = (float*)(ws + OFF_DTRAW);
  bf16*  ybuf    = (bf16*)(ws + OFF_YBUF);

  cast_kernel<<<8192, 256, 0, stream>>>(u, u_bf, (long)ROWSTOT * D_MODEL / 4);
  cast_pad_kernel<<<17152, 256, 0, stream>>>(w_in, win_bf);
  gemm1_kernel<<<2304, 256, 0, stream>>>(u_bf, win_bf, z_bf, xbc_bf, dt_raw);
  dt_scan_kernel<<<1024, 256, 0, stream>>>(dt_raw, dt_bias, A_log, dtv, dacs);
  conv_kernel<<<dim3(17, SEQLEN, 2), 256, 0, stream>>>(xbc_bf, conv_w, conv_b, x_bf, B_bf, C_bf, BT_bf);
  cb_kernel<<<16, 256, 0, stream>>>(C_bf, B_bf, CBb);
  ssm_diag_kernel<<<1024, 256, 0, stream>>>(x_bf, BT_bf, CBb, dtv, dacs, Dskip, ybuf, states);
  state_scan_kernel<<<128, 256, 0, stream>>>(states, dacs, prevb);
  yoff_kernel<<<1024, 256, 0, stream>>>(C_bf, prevb, dacs, ybuf);
  cast_kernel<<<8192, 256, 0, stream>>>(w_out, wout_bf, (long)D_MODEL * D_INNER / 4);
  gate_norm_kernel<<<ROWSTOT, 256, 0, stream>>>(ybuf, z_bf, norm_w);
  gemm2_kernel<<<512, 256, 0, stream>>>(ybuf, wout_bf, out);
}

// Round 5
// 631.255 us; speedup vs baseline: 1.5848x; 1.1481x over previous
//
#include <hip/hip_runtime.h>
#include <hip/hip_bf16.h>

// Mamba2 layer, MI355X/gfx950. Round 4: BK=64 GEMM K-loop (32 MFMA per
// barrier-pair, LDS packed as [2][128][32] so bank profile is unchanged),
// conv sliding-window restructure, wider cb/state_scan grids, shfl dt_scan.

#define D_MODEL   2048
#define D_STATE   128
#define HEADDIM   64
#define CHUNK     256
#define D_INNER   4096
#define NHEADS    64
#define CONV_DIM  4352
#define D_IN_PROJ 8512
#define SEQLEN    2048
#define NC        8
#define ROWSTOT   4096
#define NPAD      8576
#define RMS_EPS   1e-5f

// ---- workspace layout (byte offsets), lifetime-overlaid ----
#define OFF_WIN   0ull
#define OFF_XBF   0ull
#define OFF_PREV  0ull
#define OFF_WOUT  16777216ull
#define OFF_UBF   35127296ull
#define OFF_DTV   35127296ull
#define OFF_DACS  36175872ull
#define OFF_BBF   37224448ull
#define OFF_CBF   38273024ull
#define OFF_CB    39321600ull
#define OFF_BT    43515904ull
#define OFF_XBC   51904512ull
#define OFF_STATE 51904512ull
#define OFF_ZBF   87556096ull
#define OFF_DTRAW 121110528ull
#define OFF_YBUF  121110528ull
#define WS_NEEDED 154664960ull

typedef __hip_bfloat16 bf16;
typedef __bf16 bfrag8 __attribute__((ext_vector_type(8)));
typedef float  f32x4v __attribute__((ext_vector_type(4)));

__device__ __forceinline__ f32x4v mfma16(bfrag8 a, bfrag8 b, f32x4v c) {
  return __builtin_amdgcn_mfma_f32_16x16x32_bf16(a, b, c, 0, 0, 0);
}

__device__ __forceinline__ void gload_lds16(const void* g, void* l) {
  __builtin_amdgcn_global_load_lds((const __attribute__((address_space(1))) void*)g,
                                   (__attribute__((address_space(3))) void*)l, 16, 0, 0);
}

__device__ __forceinline__ bf16 f2b(float x) { return __float2bfloat16(x); }
__device__ __forceinline__ float b2f(bf16 x) { return __bfloat162float(x); }
__device__ __forceinline__ float siluf(float x) { return x / (1.f + __expf(-x)); }

// ---------------- cast kernels ----------------
__global__ __launch_bounds__(256) void cast_kernel(const float* __restrict__ in,
                                                   bf16* __restrict__ out, long n4) {
  long i = (long)blockIdx.x * 256 + threadIdx.x;
  if (i >= n4) return;
  float4 v = ((const float4*)in)[i];
  bf16* o = out + i * 4;
  o[0] = f2b(v.x); o[1] = f2b(v.y); o[2] = f2b(v.z); o[3] = f2b(v.w);
}

__global__ __launch_bounds__(256) void cast_pad_kernel(const float* __restrict__ in,
                                                       bf16* __restrict__ out) {
  long i = (long)blockIdx.x * 256 + threadIdx.x;
  long e = i * 4;
  if (e >= (long)NPAD * D_MODEL) return;
  long row = e / D_MODEL;
  bf16* o = out + e;
  if (row < D_IN_PROJ) {
    float4 v = *(const float4*)(in + e);
    o[0] = f2b(v.x); o[1] = f2b(v.y); o[2] = f2b(v.z); o[3] = f2b(v.w);
  } else {
    bf16 z = f2b(0.f);
    o[0] = z; o[1] = z; o[2] = z; o[3] = z;
  }
}

// BK=64 staging: 4 calls/thread per operand; chunk->lane map reordered so LDS
// lands as [half][128][32] (two BK=32 sub-tiles) -> ds_read bank-free.
#define STAGE64(SRC, DST, base_row, Kld, kt)                                     \
  {                                                                              \
    int ci = (j * 4 + w) * 64 + lane;          /* 0..1023 */                     \
    int half = ci >> 9, cj = ci & 511;                                           \
    int r = cj >> 2, ko = half * 32 + (cj & 3) * 8;                              \
    gload_lds16(SRC + (base_row + r) * (long)Kld + kt + ko,                      \
                (char*)DST + (j * 4 + w) * 1024);                                \
  }

// ---------------- GEMM1: zxbcdt, split epilogue; supertile swizzle; BK=64 ----
__global__ __launch_bounds__(256) void gemm1_kernel(const bf16* __restrict__ A,
                                                    const bf16* __restrict__ B,
                                                    bf16* __restrict__ zb,
                                                    bf16* __restrict__ xbc,
                                                    float* __restrict__ dtraw) {
  int pid = blockIdx.x;
  int t = pid & 127, s = pid >> 7;
  int sm = s / 9, sn = s % 9;
  int tm = sm * 16 + (t & 15);
  int tn = sn * 8 + (t >> 4);
  if (tn >= 67) return;
  long row0 = (long)tm * 128, col0 = (long)tn * 128;

  __shared__ __align__(16) bf16 As[2 * 128 * 32];
  __shared__ __align__(16) bf16 Bs[2 * 128 * 32];
  int tid = threadIdx.x, lane = tid & 63, w = tid >> 6;
  int wr = w >> 1, wc = w & 1, r16 = lane & 15, q = lane >> 4;
  const int K = D_MODEL;
  f32x4v zero4 = {0.f, 0.f, 0.f, 0.f};
  f32x4v acc[4][4];
#pragma unroll
  for (int i = 0; i < 4; ++i)
#pragma unroll
    for (int j = 0; j < 4; ++j) acc[i][j] = zero4;

  for (int kt = 0; kt < K; kt += 64) {
    __syncthreads();
#pragma unroll
    for (int j = 0; j < 4; ++j) {
      STAGE64(A, As, row0, K, kt);
      STAGE64(B, Bs, col0, K, kt);
    }
    __syncthreads();
#pragma unroll
    for (int ks = 0; ks < 2; ++ks) {
      const bf16* Ab = As + ks * 4096;
      const bf16* Bb = Bs + ks * 4096;
      bfrag8 af[4], bfv[4];
#pragma unroll
      for (int i = 0; i < 4; ++i) af[i]  = *(const bfrag8*)(Ab + (wr * 64 + i * 16 + r16) * 32 + q * 8);
#pragma unroll
      for (int i = 0; i < 4; ++i) bfv[i] = *(const bfrag8*)(Bb + (wc * 64 + i * 16 + r16) * 32 + q * 8);
#pragma unroll
      for (int i = 0; i < 4; ++i)
#pragma unroll
        for (int j = 0; j < 4; ++j) acc[i][j] = mfma16(af[i], bfv[j], acc[i][j]);
    }
  }
#pragma unroll
  for (int i = 0; i < 4; ++i)
#pragma unroll
    for (int j = 0; j < 4; ++j) {
      long col = col0 + wc * 64 + j * 16 + r16;
#pragma unroll
      for (int r = 0; r < 4; ++r) {
        long row = row0 + wr * 64 + i * 16 + q * 4 + r;
        float v = acc[i][j][r];
        if (col < D_INNER)                       zb[row * D_INNER + col] = f2b(v);
        else if (col < D_INNER + CONV_DIM)       xbc[row * CONV_DIM + (col - D_INNER)] = f2b(v);
        else if (col < D_IN_PROJ)                dtraw[row * NHEADS + (col - D_INNER - CONV_DIM)] = v;
      }
    }
}

// ---------------- GEMM2: supertile swizzle; BK=64 ----------------
__global__ __launch_bounds__(256) void gemm2_kernel(const bf16* __restrict__ A,
                                                    const bf16* __restrict__ B,
                                                    float* __restrict__ C) {
  int pid = blockIdx.x;
  int t = pid & 63, s = pid >> 6;
  int sm = s >> 1, sn = s & 1;
  int tm = sm * 8 + (t & 7);
  int tn = sn * 8 + (t >> 3);
  long row0 = (long)tm * 128, col0 = (long)tn * 128;

  __shared__ __align__(16) bf16 As[2 * 128 * 32];
  __shared__ __align__(16) bf16 Bs[2 * 128 * 32];
  int tid = threadIdx.x, lane = tid & 63, w = tid >> 6;
  int wr = w >> 1, wc = w & 1, r16 = lane & 15, q = lane >> 4;
  const int K = D_INNER, ldc = D_MODEL;
  f32x4v zero4 = {0.f, 0.f, 0.f, 0.f};
  f32x4v acc[4][4];
#pragma unroll
  for (int i = 0; i < 4; ++i)
#pragma unroll
    for (int j = 0; j < 4; ++j) acc[i][j] = zero4;

  for (int kt = 0; kt < K; kt += 64) {
    __syncthreads();
#pragma unroll
    for (int j = 0; j < 4; ++j) {
      STAGE64(A, As, row0, K, kt);
      STAGE64(B, Bs, col0, K, kt);
    }
    __syncthreads();
#pragma unroll
    for (int ks = 0; ks < 2; ++ks) {
      const bf16* Ab = As + ks * 4096;
      const bf16* Bb = Bs + ks * 4096;
      bfrag8 af[4], bfv[4];
#pragma unroll
      for (int i = 0; i < 4; ++i) af[i]  = *(const bfrag8*)(Ab + (wr * 64 + i * 16 + r16) * 32 + q * 8);
#pragma unroll
      for (int i = 0; i < 4; ++i) bfv[i] = *(const bfrag8*)(Bb + (wc * 64 + i * 16 + r16) * 32 + q * 8);
#pragma unroll
      for (int i = 0; i < 4; ++i)
#pragma unroll
        for (int j = 0; j < 4; ++j) acc[i][j] = mfma16(af[i], bfv[j], acc[i][j]);
    }
  }
#pragma unroll
  for (int i = 0; i < 4; ++i)
#pragma unroll
    for (int j = 0; j < 4; ++j)
#pragma unroll
      for (int r = 0; r < 4; ++r) {
        long row = row0 + wr * 64 + i * 16 + q * 4 + r;
        long col = col0 + wc * 64 + j * 16 + r16;
        C[row * ldc + col] = acc[i][j][r];
      }
}

// ---------------- dt softplus + per-chunk cumsum (shfl scan, 1 barrier) ------
__global__ __launch_bounds__(256) void dt_scan_kernel(const float* __restrict__ dtraw,
    const float* __restrict__ dt_bias, const float* __restrict__ A_log,
    float* __restrict__ dtv_buf, float* __restrict__ dacs_buf) {
  int blk = blockIdx.x;
  int c = blk & 7, h = (blk >> 3) & 63, b = blk >> 9;
  int s = threadIdx.x, lane = s & 63, w = s >> 6;
  long row = (long)b * SEQLEN + c * CHUNK + s;
  float raw = dtraw[row * NHEADS + h] + dt_bias[h];
  float dtv = fmaxf(raw, 0.f) + log1pf(__expf(-fabsf(raw)));
  float A = -__expf(A_log[h]);
  float x = dtv * A;
#pragma unroll
  for (int off = 1; off < 64; off <<= 1) {
    float y = __shfl_up(x, off);
    if (lane >= off) x += y;
  }
  __shared__ __align__(16) float wsum[4];
  if (lane == 63) wsum[w] = x;
  __syncthreads();
  float pre = 0.f;
#pragma unroll
  for (int i = 0; i < 4; ++i) pre += (i < w) ? wsum[i] : 0.f;
  long o = ((long)(b * NHEADS + h) * NC + c) * CHUNK + s;
  dtv_buf[o] = dtv;
  dacs_buf[o] = x + pre;
}

// ---------------- conv1d + SiLU: 8 l per thread, sliding window -------------
__global__ __launch_bounds__(256) void conv_kernel(const bf16* __restrict__ xbc,
    const float* __restrict__ conv_w, const float* __restrict__ conv_b,
    bf16* __restrict__ xo, bf16* __restrict__ Bo, bf16* __restrict__ Co,
    bf16* __restrict__ BT) {
  int cidx = blockIdx.x * 256 + threadIdx.x;
  int l0 = blockIdx.y * 8, b = blockIdx.z;
  float4 wv = *(const float4*)(conv_w + cidx * 4);
  float bias = conv_b[cidx];
  const bf16* base = xbc + (long)b * SEQLEN * CONV_DIM + cidx;
  float win[11];
#pragma unroll
  for (int k = 0; k < 11; ++k) {
    int ls = l0 - 3 + k;
    win[k] = (ls >= 0) ? b2f(base[(long)ls * CONV_DIM]) : 0.f;
  }
  int cgrp = (cidx < D_INNER) ? 0 : ((cidx < D_INNER + D_STATE) ? 1 : 2);
  int n = cidx - D_INNER;            // valid for cgrp 1
  int n2 = cidx - D_INNER - D_STATE; // valid for cgrp 2
  int cch = l0 >> 8;                 // chunk index (l0..l0+7 same chunk)
#pragma unroll
  for (int j = 0; j < 8; ++j) {
    float acc = bias + wv.x * win[j] + wv.y * win[j + 1] + wv.z * win[j + 2] + wv.w * win[j + 3];
    bf16 o = f2b(siluf(acc));
    int l = l0 + j;
    long rowo = (long)b * SEQLEN + l;
    if (cgrp == 0) {
      xo[rowo * D_INNER + cidx] = o;
    } else if (cgrp == 1) {
      Bo[rowo * D_STATE + n] = o;
      BT[(((long)b * NC + cch) * D_STATE + n) * CHUNK + (l & 255)] = o;
    } else {
      Co[rowo * D_STATE + n2] = o;
    }
  }
}

// ---------------- CB[l,s] per (b,chunk), 4 st-tiles per block ----------------
__global__ __launch_bounds__(256) void cb_kernel(const bf16* __restrict__ Cg,
                                                 const bf16* __restrict__ Bg,
                                                 float* __restrict__ CB) {
  int blk = blockIdx.x;                  // (b*8+c)*4 + stile
  int stile = blk & 3, bc = blk >> 2;
  int c = bc & 7, b = bc >> 3;
  int tid = threadIdx.x, lane = tid & 63, w = tid >> 6, r16 = lane & 15, q = lane >> 4;
  const bf16* Cb = Cg + ((long)b * SEQLEN + c * CHUNK) * D_STATE;
  const bf16* Bb = Bg + ((long)b * SEQLEN + c * CHUNK) * D_STATE;
  bfrag8 af[4][4];
#pragma unroll
  for (int lt = 0; lt < 4; ++lt)
#pragma unroll
    for (int kk = 0; kk < 4; ++kk)
      af[lt][kk] = *(const bfrag8*)(Cb + (long)(w * 64 + lt * 16 + r16) * D_STATE + kk * 32 + q * 8);
  float* CBb = CB + (long)bc * CHUNK * CHUNK;
  f32x4v zero4 = {0.f, 0.f, 0.f, 0.f};
  for (int st = stile * 4; st < stile * 4 + 4; ++st) {
    f32x4v acc[4] = {zero4, zero4, zero4, zero4};
#pragma unroll
    for (int kk = 0; kk < 4; ++kk) {
      bfrag8 bfv = *(const bfrag8*)(Bb + (long)(st * 16 + r16) * D_STATE + kk * 32 + q * 8);
#pragma unroll
      for (int lt = 0; lt < 4; ++lt) acc[lt] = mfma16(af[lt][kk], bfv, acc[lt]);
    }
#pragma unroll
    for (int lt = 0; lt < 4; ++lt)
#pragma unroll
      for (int r = 0; r < 4; ++r)
        CBb[(long)(w * 64 + lt * 16 + q * 4 + r) * CHUNK + st * 16 + r16] = acc[lt][r];
  }
}

// ---------------- per (b,chunk,head): Y_diag + skip, chunk states ------------
__global__ __launch_bounds__(256) void ssm_diag_kernel(
    const bf16* __restrict__ xg, const bf16* __restrict__ BT,
    const float* __restrict__ CB, const float* __restrict__ dtv_buf,
    const float* __restrict__ dacs_buf, const float* __restrict__ Dskip,
    bf16* __restrict__ ybuf, float* __restrict__ states) {
  int blk = blockIdx.x;
  int h = blk & 63, cc = (blk >> 6) & 7, b = blk >> 9;
  int tid = threadIdx.x, lane = tid & 63, w = tid >> 6, r16 = lane & 15, q = lane >> 4;

  __shared__ __align__(16) __bf16 xT[HEADDIM][264];
  __shared__ __align__(16) float cs_s[CHUNK];
  __shared__ __align__(16) float dt_s[CHUNK];
  __shared__ __align__(16) float w_s[CHUNK];

  long hco = ((long)(b * NHEADS + h) * NC + cc) * CHUNK;
  cs_s[tid] = dacs_buf[hco + tid];
  dt_s[tid] = dtv_buf[hco + tid];
  __syncthreads();
  float cl_last = cs_s[CHUNK - 1];
  w_s[tid] = __expf(cl_last - cs_s[tid]) * dt_s[tid];

  const __bf16* xbase = (const __bf16*)(xg + ((long)b * SEQLEN + cc * CHUNK) * D_INNER + h * HEADDIM);
#pragma unroll
  for (int it = 0; it < 8; ++it) {
    int e = it * 256 + tid;
    int s = e >> 3, p0 = (e & 7) * 8;
    bfrag8 xv = *(const bfrag8*)(xbase + (long)s * D_INNER + p0);
#pragma unroll
    for (int j = 0; j < 8; ++j) xT[p0 + j][s] = xv[j];
  }
  __syncthreads();

  const float* CBchunk = CB + (long)(b * NC + cc) * CHUNK * CHUNK;
  const __bf16* BTc = (const __bf16*)(BT + (((long)b * NC + cc) * D_STATE) * CHUNK);
  f32x4v zero4 = {0.f, 0.f, 0.f, 0.f};
  f32x4v accY[4][4], accS[2][4];
#pragma unroll
  for (int i = 0; i < 4; ++i)
#pragma unroll
    for (int j = 0; j < 4; ++j) accY[i][j] = zero4;
#pragma unroll
  for (int i = 0; i < 2; ++i)
#pragma unroll
    for (int j = 0; j < 4; ++j) accS[i][j] = zero4;

  int l_row[4];
  const float* CBrow[4];
#pragma unroll
  for (int lt = 0; lt < 4; ++lt) {
    l_row[lt] = w * 64 + lt * 16 + r16;
    CBrow[lt] = CBchunk + (long)l_row[lt] * CHUNK;
  }

#pragma unroll 2
  for (int ks = 0; ks < 8; ++ks) {
    int s0 = ks * 32 + q * 8;
    float4 cs0 = *(const float4*)(cs_s + s0);
    float4 cs1 = *(const float4*)(cs_s + s0 + 4);
    float4 dt0 = *(const float4*)(dt_s + s0);
    float4 dt1 = *(const float4*)(dt_s + s0 + 4);
    float4 w0  = *(const float4*)(w_s + s0);
    float4 w1  = *(const float4*)(w_s + s0 + 4);
    float csv[8] = {cs0.x, cs0.y, cs0.z, cs0.w, cs1.x, cs1.y, cs1.z, cs1.w};
    float dtv8[8] = {dt0.x, dt0.y, dt0.z, dt0.w, dt1.x, dt1.y, dt1.z, dt1.w};
    float wv8[8]  = {w0.x, w0.y, w0.z, w0.w, w1.x, w1.y, w1.z, w1.w};

    bfrag8 xf[4];
#pragma unroll
    for (int pt = 0; pt < 4; ++pt) xf[pt] = *(const bfrag8*)(&xT[pt * 16 + r16][s0]);

#pragma unroll
    for (int lt = 0; lt < 4; ++lt) {
      int l = l_row[lt];
      float cs_l = cs_s[l];
      float4 cb0 = *(const float4*)(CBrow[lt] + s0);
      float4 cb1 = *(const float4*)(CBrow[lt] + s0 + 4);
      float cbv[8] = {cb0.x, cb0.y, cb0.z, cb0.w, cb1.x, cb1.y, cb1.z, cb1.w};
      bfrag8 pf;
#pragma unroll
      for (int j = 0; j < 8; ++j) {
        float v = (s0 + j <= l)
                    ? cbv[j] * __expf(fminf(cs_l - csv[j], 0.f)) * dtv8[j]
                    : 0.f;
        pf[j] = (__bf16)v;
      }
#pragma unroll
      for (int pt = 0; pt < 4; ++pt) accY[lt][pt] = mfma16(pf, xf[pt], accY[lt][pt]);
    }

#pragma unroll
    for (int nt = 0; nt < 2; ++nt) {
      int n = w * 32 + nt * 16 + r16;
      bfrag8 braw = *(const bfrag8*)(BTc + (long)n * CHUNK + s0);
      bfrag8 bwf;
#pragma unroll
      for (int j = 0; j < 8; ++j) bwf[j] = (__bf16)((float)braw[j] * wv8[j]);
#pragma unroll
      for (int pt = 0; pt < 4; ++pt) accS[nt][pt] = mfma16(bwf, xf[pt], accS[nt][pt]);
    }
  }

  float dsk = Dskip[h];
  bf16* ybase = ybuf + ((long)b * SEQLEN + cc * CHUNK) * D_INNER + h * HEADDIM;
#pragma unroll
  for (int lt = 0; lt < 4; ++lt)
#pragma unroll
    for (int pt = 0; pt < 4; ++pt)
#pragma unroll
      for (int r = 0; r < 4; ++r) {
        int lrow = w * 64 + lt * 16 + q * 4 + r;
        int pcol = pt * 16 + r16;
        ybase[(long)lrow * D_INNER + pcol] = f2b(accY[lt][pt][r] + (float)xT[pcol][lrow] * dsk);
      }
  float* sbase = states + (long)blk * (HEADDIM * D_STATE);
#pragma unroll
  for (int nt = 0; nt < 2; ++nt)
#pragma unroll
    for (int pt = 0; pt < 4; ++pt)
#pragma unroll
      for (int r = 0; r < 4; ++r)
        sbase[(long)(pt * 16 + r16) * D_STATE + w * 32 + nt * 16 + q * 4 + r] = accS[nt][pt][r];
}

// ---------------- inter-chunk state scan (e-parallel grid) ----------------
__global__ __launch_bounds__(256) void state_scan_kernel(const float* __restrict__ states,
    const float* __restrict__ dacs, bf16* __restrict__ prevb) {
  int gid = blockIdx.x;                  // bh*32 + etile
  int et = gid & 31, bh = gid >> 5;
  int h = bh & 63, b = bh >> 6;
  int e = et * 256 + threadIdx.x;
  float dec[NC];
#pragma unroll
  for (int c = 0; c < NC; ++c)
    dec[c] = __expf(dacs[((long)(b * NHEADS + h) * NC + c) * CHUNK + (CHUNK - 1)]);
  float carry = 0.f;
#pragma unroll
  for (int c = 0; c < NC; ++c) {
    long off = ((long)((b * NC + c) * NHEADS + h)) * (HEADDIM * D_STATE) + e;
    prevb[off] = f2b(carry);
    carry = carry * dec[c] + states[off];
  }
}

// ---------------- Y_off accumulate (bf16 RMW) ----------------
__global__ __launch_bounds__(256) void yoff_kernel(const bf16* __restrict__ Cg,
    const bf16* __restrict__ prevb, const float* __restrict__ dacs,
    bf16* __restrict__ ybuf) {
  int blk = blockIdx.x;
  int h = blk & 63, cc = (blk >> 6) & 7, b = blk >> 9;
  int tid = threadIdx.x, lane = tid & 63, w = tid >> 6, r16 = lane & 15, q = lane >> 4;
  __shared__ __align__(16) float cs_s[CHUNK];
  cs_s[tid] = dacs[((long)(b * NHEADS + h) * NC + cc) * CHUNK + tid];
  __syncthreads();
  const bf16* Cb = Cg + ((long)b * SEQLEN + cc * CHUNK) * D_STATE;
  const bf16* Pb = prevb + (long)blk * (HEADDIM * D_STATE);
  f32x4v zero4 = {0.f, 0.f, 0.f, 0.f};
  f32x4v acc[4][4];
#pragma unroll
  for (int i = 0; i < 4; ++i)
#pragma unroll
    for (int j = 0; j < 4; ++j) acc[i][j] = zero4;
#pragma unroll
  for (int kk = 0; kk < 4; ++kk) {
    bfrag8 bv[4];
#pragma unroll
    for (int pt = 0; pt < 4; ++pt)
      bv[pt] = *(const bfrag8*)(Pb + (long)(pt * 16 + r16) * D_STATE + kk * 32 + q * 8);
#pragma unroll
    for (int lt = 0; lt < 4; ++lt) {
      bfrag8 av = *(const bfrag8*)(Cb + (long)(w * 64 + lt * 16 + r16) * D_STATE + kk * 32 + q * 8);
#pragma unroll
      for (int pt = 0; pt < 4; ++pt) acc[lt][pt] = mfma16(av, bv[pt], acc[lt][pt]);
    }
  }
  bf16* ybase = ybuf + ((long)b * SEQLEN + cc * CHUNK) * D_INNER + h * HEADDIM;
#pragma unroll
  for (int lt = 0; lt < 4; ++lt)
#pragma unroll
    for (int pt = 0; pt < 4; ++pt)
#pragma unroll
      for (int r = 0; r < 4; ++r) {
        int lrow = w * 64 + lt * 16 + q * 4 + r;
        float ef = __expf(cs_s[lrow]);
        bf16* p = ybase + (long)lrow * D_INNER + pt * 16 + r16;
        *p = f2b(b2f(*p) + acc[lt][pt][r] * ef);
      }
}

// ---------------- gate + RMSNorm, in-place ----------------
__global__ __launch_bounds__(256) void gate_norm_kernel(bf16* __restrict__ ybuf,
    const bf16* __restrict__ zb, const float* __restrict__ norm_w) {
  int row = blockIdx.x, tid = threadIdx.x;
  bf16* y = ybuf + (long)row * D_INNER;
  const bf16* z = zb + (long)row * D_INNER;
  float v[16];
  float ss = 0.f;
#pragma unroll
  for (int i = 0; i < 2; ++i) {
    int e = tid * 16 + i * 8;
    bfrag8 yv = *(const bfrag8*)(y + e);
    bfrag8 zv = *(const bfrag8*)(z + e);
#pragma unroll
    for (int j = 0; j < 8; ++j) {
      float a = (float)yv[j] * siluf((float)zv[j]);
      v[i * 8 + j] = a;
      ss += a * a;
    }
  }
#pragma unroll
  for (int off = 32; off > 0; off >>= 1) ss += __shfl_down(ss, off);
  __shared__ __align__(16) float red[4];
  int lane = tid & 63, w = tid >> 6;
  if (lane == 0) red[w] = ss;
  __syncthreads();
  float tot = red[0] + red[1] + red[2] + red[3];
  float scale = rsqrtf(tot * (1.f / D_INNER) + RMS_EPS);
#pragma unroll
  for (int i = 0; i < 2; ++i) {
    int e = tid * 16 + i * 8;
    float4 w0 = *(const float4*)(norm_w + e);
    float4 w1 = *(const float4*)(norm_w + e + 4);
    bfrag8 o;
    o[0] = (__bf16)(v[i * 8 + 0] * scale * w0.x);
    o[1] = (__bf16)(v[i * 8 + 1] * scale * w0.y);
    o[2] = (__bf16)(v[i * 8 + 2] * scale * w0.z);
    o[3] = (__bf16)(v[i * 8 + 3] * scale * w0.w);
    o[4] = (__bf16)(v[i * 8 + 4] * scale * w1.x);
    o[5] = (__bf16)(v[i * 8 + 5] * scale * w1.y);
    o[6] = (__bf16)(v[i * 8 + 6] * scale * w1.z);
    o[7] = (__bf16)(v[i * 8 + 7] * scale * w1.w);
    *(bfrag8*)(y + e) = o;
  }
}

// ---------------- launch ----------------
extern "C" void kernel_launch(void* const* d_in, const int* in_sizes, int n_in,
                              void* d_out, int out_size, void* d_ws, size_t ws_size,
                              hipStream_t stream) {
  if (ws_size < WS_NEEDED) return;

  const float* u       = (const float*)d_in[0];
  const float* w_in    = (const float*)d_in[1];
  const float* conv_w  = (const float*)d_in[2];
  const float* conv_b  = (const float*)d_in[3];
  const float* dt_bias = (const float*)d_in[4];
  const float* A_log   = (const float*)d_in[5];
  const float* Dskip   = (const float*)d_in[6];
  const float* norm_w  = (const float*)d_in[7];
  const float* w_out   = (const float*)d_in[8];
  float* out = (float*)d_out;

  char* ws = (char*)d_ws;
  bf16*  win_bf  = (bf16*)(ws + OFF_WIN);
  bf16*  x_bf    = (bf16*)(ws + OFF_XBF);
  bf16*  prevb   = (bf16*)(ws + OFF_PREV);
  bf16*  wout_bf = (bf16*)(ws + OFF_WOUT);
  bf16*  u_bf    = (bf16*)(ws + OFF_UBF);
  float* dtv     = (float*)(ws + OFF_DTV);
  float* dacs    = (float*)(ws + OFF_DACS);
  bf16*  B_bf    = (bf16*)(ws + OFF_BBF);
  bf16*  C_bf    = (bf16*)(ws + OFF_CBF);
  float* CBb     = (float*)(ws + OFF_CB);
  bf16*  BT_bf   = (bf16*)(ws + OFF_BT);
  bf16*  xbc_bf  = (bf16*)(ws + OFF_XBC);
  float* states  = (float*)(ws + OFF_STATE);
  bf16*  z_bf    = (bf16*)(ws + OFF_ZBF);
  float* dt_raw  = (float*)(ws + OFF_DTRAW);
  bf16*  ybuf    = (bf16*)(ws + OFF_YBUF);

  cast_kernel<<<8192, 256, 0, stream>>>(u, u_bf, (long)ROWSTOT * D_MODEL / 4);
  cast_pad_kernel<<<17152, 256, 0, stream>>>(w_in, win_bf);
  gemm1_kernel<<<2304, 256, 0, stream>>>(u_bf, win_bf, z_bf, xbc_bf, dt_raw);
  dt_scan_kernel<<<1024, 256, 0, stream>>>(dt_raw, dt_bias, A_log, dtv, dacs);
  conv_kernel<<<dim3(17, SEQLEN / 8, 2), 256, 0, stream>>>(xbc_bf, conv_w, conv_b, x_bf, B_bf, C_bf, BT_bf);
  cb_kernel<<<64, 256, 0, stream>>>(C_bf, B_bf, CBb);
  ssm_diag_kernel<<<1024, 256, 0, stream>>>(x_bf, BT_bf, CBb, dtv, dacs, Dskip, ybuf, states);
  state_scan_kernel<<<4096, 256, 0, stream>>>(states, dacs, prevb);
  yoff_kernel<<<1024, 256, 0, stream>>>(C_bf, prevb, dacs, ybuf);
  cast_kernel<<<8192, 256, 0, stream>>>(w_out, wout_bf, (long)D_MODEL * D_INNER / 4);
  gate_norm_kernel<<<ROWSTOT, 256, 0, stream>>>(ybuf, z_bf, norm_w);
  gemm2_kernel<<<512, 256, 0, stream>>>(ybuf, wout_bf, out);
}

// Round 8
// 590.547 us; speedup vs baseline: 1.6940x; 1.0689x over previous
//
#include <hip/hip_runtime.h>
#include <hip/hip_bf16.h>

// Mamba2 layer, MI355X/gfx950. Round 7: FIX ws lifetime bug from R5/R6 —
// fused cast wrote wout_bf (16.7-33.5MB) inside live win_bf (0-35.1MB), and
// conv's x_bf later clobbered wout_bf. wout cast moved back to after yoff
// (R4's proven slot). gemm structure identical to R6.

#define D_MODEL   2048
#define D_STATE   128
#define HEADDIM   64
#define CHUNK     256
#define D_INNER   4096
#define NHEADS    64
#define CONV_DIM  4352
#define D_IN_PROJ 8512
#define SEQLEN    2048
#define NC        8
#define ROWSTOT   4096
#define NPAD      8576
#define RMS_EPS   1e-5f

// ---- workspace layout (byte offsets), lifetime-overlaid ----
// S_A: win_bf(steps 0-1) -> x_bf(4-6) -> prevb(7-8)@+0 ; wout_bf(9-11)@+16MB
#define OFF_WIN   0ull
#define OFF_XBF   0ull
#define OFF_PREV  0ull
#define OFF_WOUT  16777216ull
#define OFF_UBF   35127296ull
#define OFF_DTV   35127296ull
#define OFF_DACS  36175872ull
#define OFF_BBF   37224448ull
#define OFF_CBF   38273024ull
#define OFF_CB    39321600ull
#define OFF_BT    43515904ull
#define OFF_XBC   51904512ull
#define OFF_STATE 51904512ull
#define OFF_ZBF   87556096ull
#define OFF_DTRAW 121110528ull
#define OFF_YBUF  121110528ull
#define WS_NEEDED 154664960ull

// fused-cast segment sizes (float4 units) — u and w_in ONLY
#define N4_U    2097152l
#define N4_WIN  4390912l

typedef __hip_bfloat16 bf16;
typedef __bf16 bfrag8 __attribute__((ext_vector_type(8)));
typedef float  f32x4v __attribute__((ext_vector_type(4)));

__device__ __forceinline__ f32x4v mfma16(bfrag8 a, bfrag8 b, f32x4v c) {
  return __builtin_amdgcn_mfma_f32_16x16x32_bf16(a, b, c, 0, 0, 0);
}

__device__ __forceinline__ void gload_lds16(const void* g, void* l) {
  __builtin_amdgcn_global_load_lds((const __attribute__((address_space(1))) void*)g,
                                   (__attribute__((address_space(3))) void*)l, 16, 0, 0);
}

__device__ __forceinline__ bf16 f2b(float x) { return __float2bfloat16(x); }
__device__ __forceinline__ float b2f(bf16 x) { return __bfloat162float(x); }
__device__ __forceinline__ float siluf(float x) { return x / (1.f + __expf(-x)); }

// ---------------- cast: u -> u_bf, w_in -> win_bf (padded). NOT w_out. ------
__global__ __launch_bounds__(256) void cast_all_kernel(const float* __restrict__ u,
    const float* __restrict__ w_in,
    bf16* __restrict__ u_bf, bf16* __restrict__ win_bf) {
  long i = (long)blockIdx.x * 256 + threadIdx.x;
  if (i < N4_U) {
    float4 v = ((const float4*)u)[i];
    bf16* o = u_bf + i * 4;
    o[0] = f2b(v.x); o[1] = f2b(v.y); o[2] = f2b(v.z); o[3] = f2b(v.w);
  } else if (i < N4_U + N4_WIN) {
    long e = (i - N4_U) * 4;
    long row = e / D_MODEL;
    bf16* o = win_bf + e;
    if (row < D_IN_PROJ) {
      float4 v = *(const float4*)(w_in + e);
      o[0] = f2b(v.x); o[1] = f2b(v.y); o[2] = f2b(v.z); o[3] = f2b(v.w);
    } else {
      bf16 z = f2b(0.f);
      o[0] = z; o[1] = z; o[2] = z; o[3] = z;
    }
  }
}

// ---------------- simple cast (for w_out, launched late) --------------------
__global__ __launch_bounds__(256) void cast_kernel(const float* __restrict__ in,
                                                   bf16* __restrict__ out, long n4) {
  long i = (long)blockIdx.x * 256 + threadIdx.x;
  if (i >= n4) return;
  float4 v = ((const float4*)in)[i];
  bf16* o = out + i * 4;
  o[0] = f2b(v.x); o[1] = f2b(v.y); o[2] = f2b(v.z); o[3] = f2b(v.w);
}

// ---------------- GEMM1: 256x128 tile, 512 threads, BK=64, XCD-aware swizzle
__global__ __launch_bounds__(512) void gemm1_kernel(const bf16* __restrict__ A,
                                                    const bf16* __restrict__ B,
                                                    bf16* __restrict__ zb,
                                                    bf16* __restrict__ xbc,
                                                    float* __restrict__ dtraw) {
  int pid = blockIdx.x;
  int t = pid & 63, s = pid >> 6;
  int sm = s / 9, sn = s % 9;
  int xcd = t & 7, j8 = t >> 3;
  int tm = sm * 8 + (xcd >> 1) * 2 + (j8 & 1);
  int tn = sn * 8 + (xcd & 1) * 4 + (j8 >> 1);
  if (tn >= 67) return;
  long row0 = (long)tm * 256, col0 = (long)tn * 128;

  __shared__ __align__(16) bf16 As[2 * 256 * 32];   // 32 KB
  __shared__ __align__(16) bf16 Bs[2 * 128 * 32];   // 16 KB
  int tid = threadIdx.x, lane = tid & 63, w = tid >> 6;
  int wr = w >> 1, wc = w & 1, r16 = lane & 15, q = lane >> 4;
  const int K = D_MODEL;
  f32x4v zero4 = {0.f, 0.f, 0.f, 0.f};
  f32x4v acc[4][4];
#pragma unroll
  for (int i = 0; i < 4; ++i)
#pragma unroll
    for (int j = 0; j < 4; ++j) acc[i][j] = zero4;

  for (int kt = 0; kt < K; kt += 64) {
    __syncthreads();
#pragma unroll
    for (int j = 0; j < 4; ++j) {          // A: 2048 chunks of 16B
      int ci = j * 512 + tid;
      int half = ci >> 10, cj = ci & 1023;
      int r = cj >> 2, ko = half * 32 + (cj & 3) * 8;
      gload_lds16(A + (row0 + r) * (long)K + kt + ko,
                  (char*)As + j * 8192 + w * 1024);      // wave-uniform
    }
#pragma unroll
    for (int j = 0; j < 2; ++j) {          // B: 1024 chunks of 16B
      int ci = j * 512 + tid;
      int half = ci >> 9, cj = ci & 511;
      int r = cj >> 2, ko = half * 32 + (cj & 3) * 8;
      gload_lds16(B + (col0 + r) * (long)K + kt + ko,
                  (char*)Bs + j * 8192 + w * 1024);      // wave-uniform
    }
    __syncthreads();
#pragma unroll
    for (int ks = 0; ks < 2; ++ks) {
      const bf16* Ab = As + ks * 8192;
      const bf16* Bb = Bs + ks * 4096;
      bfrag8 af[4], bfv[4];
#pragma unroll
      for (int i = 0; i < 4; ++i) af[i]  = *(const bfrag8*)(Ab + (wr * 64 + i * 16 + r16) * 32 + q * 8);
#pragma unroll
      for (int i = 0; i < 4; ++i) bfv[i] = *(const bfrag8*)(Bb + (wc * 64 + i * 16 + r16) * 32 + q * 8);
#pragma unroll
      for (int i = 0; i < 4; ++i)
#pragma unroll
        for (int j = 0; j < 4; ++j) acc[i][j] = mfma16(af[i], bfv[j], acc[i][j]);
    }
  }
#pragma unroll
  for (int i = 0; i < 4; ++i)
#pragma unroll
    for (int j = 0; j < 4; ++j) {
      long col = col0 + wc * 64 + j * 16 + r16;
#pragma unroll
      for (int r = 0; r < 4; ++r) {
        long row = row0 + wr * 64 + i * 16 + q * 4 + r;
        float v = acc[i][j][r];
        if (col < D_INNER)                       zb[row * D_INNER + col] = f2b(v);
        else if (col < D_INNER + CONV_DIM)       xbc[row * CONV_DIM + (col - D_INNER)] = f2b(v);
        else if (col < D_IN_PROJ)                dtraw[row * NHEADS + (col - D_INNER - CONV_DIM)] = v;
      }
    }
}

// ---------------- GEMM2: 128x128, BK=64, XCD-aware swizzle ----------------
__global__ __launch_bounds__(256) void gemm2_kernel(const bf16* __restrict__ A,
                                                    const bf16* __restrict__ B,
                                                    float* __restrict__ C) {
  int pid = blockIdx.x;
  int t = pid & 63, s = pid >> 6;
  int sm = s >> 1, sn = s & 1;
  int xcd = t & 7, j8 = t >> 3;
  int tm = sm * 8 + (xcd >> 1) * 2 + (j8 & 1);
  int tn = sn * 8 + (xcd & 1) * 4 + (j8 >> 1);
  long row0 = (long)tm * 128, col0 = (long)tn * 128;

  __shared__ __align__(16) bf16 As[2 * 128 * 32];
  __shared__ __align__(16) bf16 Bs[2 * 128 * 32];
  int tid = threadIdx.x, lane = tid & 63, w = tid >> 6;
  int wr = w >> 1, wc = w & 1, r16 = lane & 15, q = lane >> 4;
  const int K = D_INNER, ldc = D_MODEL;
  f32x4v zero4 = {0.f, 0.f, 0.f, 0.f};
  f32x4v acc[4][4];
#pragma unroll
  for (int i = 0; i < 4; ++i)
#pragma unroll
    for (int j = 0; j < 4; ++j) acc[i][j] = zero4;

  for (int kt = 0; kt < K; kt += 64) {
    __syncthreads();
#pragma unroll
    for (int j = 0; j < 4; ++j) {
      int ci = (j * 4 + w) * 64 + lane;
      int half = ci >> 9, cj = ci & 511;
      int r = cj >> 2, ko = half * 32 + (cj & 3) * 8;
      gload_lds16(A + (row0 + r) * (long)K + kt + ko,
                  (char*)As + (j * 4 + w) * 1024);       // wave-uniform
    }
#pragma unroll
    for (int j = 0; j < 4; ++j) {
      int ci = (j * 4 + w) * 64 + lane;
      int half = ci >> 9, cj = ci & 511;
      int r = cj >> 2, ko = half * 32 + (cj & 3) * 8;
      gload_lds16(B + (col0 + r) * (long)K + kt + ko,
                  (char*)Bs + (j * 4 + w) * 1024);       // wave-uniform
    }
    __syncthreads();
#pragma unroll
    for (int ks = 0; ks < 2; ++ks) {
      const bf16* Ab = As + ks * 4096;
      const bf16* Bb = Bs + ks * 4096;
      bfrag8 af[4], bfv[4];
#pragma unroll
      for (int i = 0; i < 4; ++i) af[i]  = *(const bfrag8*)(Ab + (wr * 64 + i * 16 + r16) * 32 + q * 8);
#pragma unroll
      for (int i = 0; i < 4; ++i) bfv[i] = *(const bfrag8*)(Bb + (wc * 64 + i * 16 + r16) * 32 + q * 8);
#pragma unroll
      for (int i = 0; i < 4; ++i)
#pragma unroll
        for (int j = 0; j < 4; ++j) acc[i][j] = mfma16(af[i], bfv[j], acc[i][j]);
    }
  }
#pragma unroll
  for (int i = 0; i < 4; ++i)
#pragma unroll
    for (int j = 0; j < 4; ++j)
#pragma unroll
      for (int r = 0; r < 4; ++r) {
        long row = row0 + wr * 64 + i * 16 + q * 4 + r;
        long col = col0 + wc * 64 + j * 16 + r16;
        C[row * ldc + col] = acc[i][j][r];
      }
}

// ---------------- dt softplus + per-chunk cumsum (shfl scan) ----------------
__global__ __launch_bounds__(256) void dt_scan_kernel(const float* __restrict__ dtraw,
    const float* __restrict__ dt_bias, const float* __restrict__ A_log,
    float* __restrict__ dtv_buf, float* __restrict__ dacs_buf) {
  int blk = blockIdx.x;
  int c = blk & 7, h = (blk >> 3) & 63, b = blk >> 9;
  int s = threadIdx.x, lane = s & 63, w = s >> 6;
  long row = (long)b * SEQLEN + c * CHUNK + s;
  float raw = dtraw[row * NHEADS + h] + dt_bias[h];
  float dtv = fmaxf(raw, 0.f) + log1pf(__expf(-fabsf(raw)));
  float A = -__expf(A_log[h]);
  float x = dtv * A;
#pragma unroll
  for (int off = 1; off < 64; off <<= 1) {
    float y = __shfl_up(x, off);
    if (lane >= off) x += y;
  }
  __shared__ __align__(16) float wsum[4];
  if (lane == 63) wsum[w] = x;
  __syncthreads();
  float pre = 0.f;
#pragma unroll
  for (int i = 0; i < 4; ++i) pre += (i < w) ? wsum[i] : 0.f;
  long o = ((long)(b * NHEADS + h) * NC + c) * CHUNK + s;
  dtv_buf[o] = dtv;
  dacs_buf[o] = x + pre;
}

// ---------------- conv1d + SiLU: 8 l per thread, sliding window -------------
__global__ __launch_bounds__(256) void conv_kernel(const bf16* __restrict__ xbc,
    const float* __restrict__ conv_w, const float* __restrict__ conv_b,
    bf16* __restrict__ xo, bf16* __restrict__ Bo, bf16* __restrict__ Co,
    bf16* __restrict__ BT) {
  int cidx = blockIdx.x * 256 + threadIdx.x;
  int l0 = blockIdx.y * 8, b = blockIdx.z;
  float4 wv = *(const float4*)(conv_w + cidx * 4);
  float bias = conv_b[cidx];
  const bf16* base = xbc + (long)b * SEQLEN * CONV_DIM + cidx;
  float win[11];
#pragma unroll
  for (int k = 0; k < 11; ++k) {
    int ls = l0 - 3 + k;
    win[k] = (ls >= 0) ? b2f(base[(long)ls * CONV_DIM]) : 0.f;
  }
  int cgrp = (cidx < D_INNER) ? 0 : ((cidx < D_INNER + D_STATE) ? 1 : 2);
  int n = cidx - D_INNER;
  int n2 = cidx - D_INNER - D_STATE;
  int cch = l0 >> 8;
#pragma unroll
  for (int j = 0; j < 8; ++j) {
    float acc = bias + wv.x * win[j] + wv.y * win[j + 1] + wv.z * win[j + 2] + wv.w * win[j + 3];
    bf16 o = f2b(siluf(acc));
    int l = l0 + j;
    long rowo = (long)b * SEQLEN + l;
    if (cgrp == 0) {
      xo[rowo * D_INNER + cidx] = o;
    } else if (cgrp == 1) {
      Bo[rowo * D_STATE + n] = o;
      BT[(((long)b * NC + cch) * D_STATE + n) * CHUNK + (l & 255)] = o;
    } else {
      Co[rowo * D_STATE + n2] = o;
    }
  }
}

// ---------------- CB[l,s] per (b,chunk), 4 st-tiles per block ----------------
__global__ __launch_bounds__(256) void cb_kernel(const bf16* __restrict__ Cg,
                                                 const bf16* __restrict__ Bg,
                                                 float* __restrict__ CB) {
  int blk = blockIdx.x;
  int stile = blk & 3, bc = blk >> 2;
  int c = bc & 7, b = bc >> 3;
  int tid = threadIdx.x, lane = tid & 63, w = tid >> 6, r16 = lane & 15, q = lane >> 4;
  const bf16* Cb = Cg + ((long)b * SEQLEN + c * CHUNK) * D_STATE;
  const bf16* Bb = Bg + ((long)b * SEQLEN + c * CHUNK) * D_STATE;
  bfrag8 af[4][4];
#pragma unroll
  for (int lt = 0; lt < 4; ++lt)
#pragma unroll
    for (int kk = 0; kk < 4; ++kk)
      af[lt][kk] = *(const bfrag8*)(Cb + (long)(w * 64 + lt * 16 + r16) * D_STATE + kk * 32 + q * 8);
  float* CBb = CB + (long)bc * CHUNK * CHUNK;
  f32x4v zero4 = {0.f, 0.f, 0.f, 0.f};
  for (int st = stile * 4; st < stile * 4 + 4; ++st) {
    f32x4v acc[4] = {zero4, zero4, zero4, zero4};
#pragma unroll
    for (int kk = 0; kk < 4; ++kk) {
      bfrag8 bfv = *(const bfrag8*)(Bb + (long)(st * 16 + r16) * D_STATE + kk * 32 + q * 8);
#pragma unroll
      for (int lt = 0; lt < 4; ++lt) acc[lt] = mfma16(af[lt][kk], bfv, acc[lt]);
    }
#pragma unroll
    for (int lt = 0; lt < 4; ++lt)
#pragma unroll
      for (int r = 0; r < 4; ++r)
        CBb[(long)(w * 64 + lt * 16 + q * 4 + r) * CHUNK + st * 16 + r16] = acc[lt][r];
  }
}

// ---------------- per (b,chunk,head): Y_diag + skip, chunk states ------------
__global__ __launch_bounds__(256) void ssm_diag_kernel(
    const bf16* __restrict__ xg, const bf16* __restrict__ BT,
    const float* __restrict__ CB, const float* __restrict__ dtv_buf,
    const float* __restrict__ dacs_buf, const float* __restrict__ Dskip,
    bf16* __restrict__ ybuf, float* __restrict__ states) {
  int blk = blockIdx.x;
  int h = blk & 63, cc = (blk >> 6) & 7, b = blk >> 9;
  int tid = threadIdx.x, lane = tid & 63, w = tid >> 6, r16 = lane & 15, q = lane >> 4;

  __shared__ __align__(16) __bf16 xT[HEADDIM][264];
  __shared__ __align__(16) float cs_s[CHUNK];
  __shared__ __align__(16) float dt_s[CHUNK];
  __shared__ __align__(16) float w_s[CHUNK];

  long hco = ((long)(b * NHEADS + h) * NC + cc) * CHUNK;
  cs_s[tid] = dacs_buf[hco + tid];
  dt_s[tid] = dtv_buf[hco + tid];
  __syncthreads();
  float cl_last = cs_s[CHUNK - 1];
  w_s[tid] = __expf(cl_last - cs_s[tid]) * dt_s[tid];

  const __bf16* xbase = (const __bf16*)(xg + ((long)b * SEQLEN + cc * CHUNK) * D_INNER + h * HEADDIM);
#pragma unroll
  for (int it = 0; it < 8; ++it) {
    int e = it * 256 + tid;
    int s = e >> 3, p0 = (e & 7) * 8;
    bfrag8 xv = *(const bfrag8*)(xbase + (long)s * D_INNER + p0);
#pragma unroll
    for (int j = 0; j < 8; ++j) xT[p0 + j][s] = xv[j];
  }
  __syncthreads();

  const float* CBchunk = CB + (long)(b * NC + cc) * CHUNK * CHUNK;
  const __bf16* BTc = (const __bf16*)(BT + (((long)b * NC + cc) * D_STATE) * CHUNK);
  f32x4v zero4 = {0.f, 0.f, 0.f, 0.f};
  f32x4v accY[4][4], accS[2][4];
#pragma unroll
  for (int i = 0; i < 4; ++i)
#pragma unroll
    for (int j = 0; j < 4; ++j) accY[i][j] = zero4;
#pragma unroll
  for (int i = 0; i < 2; ++i)
#pragma unroll
    for (int j = 0; j < 4; ++j) accS[i][j] = zero4;

  int l_row[4];
  const float* CBrow[4];
#pragma unroll
  for (int lt = 0; lt < 4; ++lt) {
    l_row[lt] = w * 64 + lt * 16 + r16;
    CBrow[lt] = CBchunk + (long)l_row[lt] * CHUNK;
  }

#pragma unroll 2
  for (int ks = 0; ks < 8; ++ks) {
    int s0 = ks * 32 + q * 8;
    float4 cs0 = *(const float4*)(cs_s + s0);
    float4 cs1 = *(const float4*)(cs_s + s0 + 4);
    float4 dt0 = *(const float4*)(dt_s + s0);
    float4 dt1 = *(const float4*)(dt_s + s0 + 4);
    float4 w0  = *(const float4*)(w_s + s0);
    float4 w1  = *(const float4*)(w_s + s0 + 4);
    float csv[8] = {cs0.x, cs0.y, cs0.z, cs0.w, cs1.x, cs1.y, cs1.z, cs1.w};
    float dtv8[8] = {dt0.x, dt0.y, dt0.z, dt0.w, dt1.x, dt1.y, dt1.z, dt1.w};
    float wv8[8]  = {w0.x, w0.y, w0.z, w0.w, w1.x, w1.y, w1.z, w1.w};

    bfrag8 xf[4];
#pragma unroll
    for (int pt = 0; pt < 4; ++pt) xf[pt] = *(const bfrag8*)(&xT[pt * 16 + r16][s0]);

#pragma unroll
    for (int lt = 0; lt < 4; ++lt) {
      int l = l_row[lt];
      float cs_l = cs_s[l];
      float4 cb0 = *(const float4*)(CBrow[lt] + s0);
      float4 cb1 = *(const float4*)(CBrow[lt] + s0 + 4);
      float cbv[8] = {cb0.x, cb0.y, cb0.z, cb0.w, cb1.x, cb1.y, cb1.z, cb1.w};
      bfrag8 pf;
#pragma unroll
      for (int j = 0; j < 8; ++j) {
        float v = (s0 + j <= l)
                    ? cbv[j] * __expf(fminf(cs_l - csv[j], 0.f)) * dtv8[j]
                    : 0.f;
        pf[j] = (__bf16)v;
      }
#pragma unroll
      for (int pt = 0; pt < 4; ++pt) accY[lt][pt] = mfma16(pf, xf[pt], accY[lt][pt]);
    }

#pragma unroll
    for (int nt = 0; nt < 2; ++nt) {
      int n = w * 32 + nt * 16 + r16;
      bfrag8 braw = *(const bfrag8*)(BTc + (long)n * CHUNK + s0);
      bfrag8 bwf;
#pragma unroll
      for (int j = 0; j < 8; ++j) bwf[j] = (__bf16)((float)braw[j] * wv8[j]);
#pragma unroll
      for (int pt = 0; pt < 4; ++pt) accS[nt][pt] = mfma16(bwf, xf[pt], accS[nt][pt]);
    }
  }

  float dsk = Dskip[h];
  bf16* ybase = ybuf + ((long)b * SEQLEN + cc * CHUNK) * D_INNER + h * HEADDIM;
#pragma unroll
  for (int lt = 0; lt < 4; ++lt)
#pragma unroll
    for (int pt = 0; pt < 4; ++pt)
#pragma unroll
      for (int r = 0; r < 4; ++r) {
        int lrow = w * 64 + lt * 16 + q * 4 + r;
        int pcol = pt * 16 + r16;
        ybase[(long)lrow * D_INNER + pcol] = f2b(accY[lt][pt][r] + (float)xT[pcol][lrow] * dsk);
      }
  float* sbase = states + (long)blk * (HEADDIM * D_STATE);
#pragma unroll
  for (int nt = 0; nt < 2; ++nt)
#pragma unroll
    for (int pt = 0; pt < 4; ++pt)
#pragma unroll
      for (int r = 0; r < 4; ++r)
        sbase[(long)(pt * 16 + r16) * D_STATE + w * 32 + nt * 16 + q * 4 + r] = accS[nt][pt][r];
}

// ---------------- inter-chunk state scan (e-parallel grid) ----------------
__global__ __launch_bounds__(256) void state_scan_kernel(const float* __restrict__ states,
    const float* __restrict__ dacs, bf16* __restrict__ prevb) {
  int gid = blockIdx.x;
  int et = gid & 31, bh = gid >> 5;
  int h = bh & 63, b = bh >> 6;
  int e = et * 256 + threadIdx.x;
  float dec[NC];
#pragma unroll
  for (int c = 0; c < NC; ++c)
    dec[c] = __expf(dacs[((long)(b * NHEADS + h) * NC + c) * CHUNK + (CHUNK - 1)]);
  float carry = 0.f;
#pragma unroll
  for (int c = 0; c < NC; ++c) {
    long off = ((long)((b * NC + c) * NHEADS + h)) * (HEADDIM * D_STATE) + e;
    prevb[off] = f2b(carry);
    carry = carry * dec[c] + states[off];
  }
}

// ---------------- Y_off accumulate (bf16 RMW) ----------------
__global__ __launch_bounds__(256) void yoff_kernel(const bf16* __restrict__ Cg,
    const bf16* __restrict__ prevb, const float* __restrict__ dacs,
    bf16* __restrict__ ybuf) {
  int blk = blockIdx.x;
  int h = blk & 63, cc = (blk >> 6) & 7, b = blk >> 9;
  int tid = threadIdx.x, lane = tid & 63, w = tid >> 6, r16 = lane & 15, q = lane >> 4;
  __shared__ __align__(16) float cs_s[CHUNK];
  cs_s[tid] = dacs[((long)(b * NHEADS + h) * NC + cc) * CHUNK + tid];
  __syncthreads();
  const bf16* Cb = Cg + ((long)b * SEQLEN + cc * CHUNK) * D_STATE;
  const bf16* Pb = prevb + (long)blk * (HEADDIM * D_STATE);
  f32x4v zero4 = {0.f, 0.f, 0.f, 0.f};
  f32x4v acc[4][4];
#pragma unroll
  for (int i = 0; i < 4; ++i)
#pragma unroll
    for (int j = 0; j < 4; ++j) acc[i][j] = zero4;
#pragma unroll
  for (int kk = 0; kk < 4; ++kk) {
    bfrag8 bv[4];
#pragma unroll
    for (int pt = 0; pt < 4; ++pt)
      bv[pt] = *(const bfrag8*)(Pb + (long)(pt * 16 + r16) * D_STATE + kk * 32 + q * 8);
#pragma unroll
    for (int lt = 0; lt < 4; ++lt) {
      bfrag8 av = *(const bfrag8*)(Cb + (long)(w * 64 + lt * 16 + r16) * D_STATE + kk * 32 + q * 8);
#pragma unroll
      for (int pt = 0; pt < 4; ++pt) acc[lt][pt] = mfma16(av, bv[pt], acc[lt][pt]);
    }
  }
  bf16* ybase = ybuf + ((long)b * SEQLEN + cc * CHUNK) * D_INNER + h * HEADDIM;
#pragma unroll
  for (int lt = 0; lt < 4; ++lt)
#pragma unroll
    for (int pt = 0; pt < 4; ++pt)
#pragma unroll
      for (int r = 0; r < 4; ++r) {
        int lrow = w * 64 + lt * 16 + q * 4 + r;
        float ef = __expf(cs_s[lrow]);
        bf16* p = ybase + (long)lrow * D_INNER + pt * 16 + r16;
        *p = f2b(b2f(*p) + acc[lt][pt][r] * ef);
      }
}

// ---------------- gate + RMSNorm, in-place ----------------
__global__ __launch_bounds__(256) void gate_norm_kernel(bf16* __restrict__ ybuf,
    const bf16* __restrict__ zb, const float* __restrict__ norm_w) {
  int row = blockIdx.x, tid = threadIdx.x;
  bf16* y = ybuf + (long)row * D_INNER;
  const bf16* z = zb + (long)row * D_INNER;
  float v[16];
  float ss = 0.f;
#pragma unroll
  for (int i = 0; i < 2; ++i) {
    int e = tid * 16 + i * 8;
    bfrag8 yv = *(const bfrag8*)(y + e);
    bfrag8 zv = *(const bfrag8*)(z + e);
#pragma unroll
    for (int j = 0; j < 8; ++j) {
      float a = (float)yv[j] * siluf((float)zv[j]);
      v[i * 8 + j] = a;
      ss += a * a;
    }
  }
#pragma unroll
  for (int off = 32; off > 0; off >>= 1) ss += __shfl_down(ss, off);
  __shared__ __align__(16) float red[4];
  int lane = tid & 63, w = tid >> 6;
  if (lane == 0) red[w] = ss;
  __syncthreads();
  float tot = red[0] + red[1] + red[2] + red[3];
  float scale = rsqrtf(tot * (1.f / D_INNER) + RMS_EPS);
#pragma unroll
  for (int i = 0; i < 2; ++i) {
    int e = tid * 16 + i * 8;
    float4 w0 = *(const float4*)(norm_w + e);
    float4 w1 = *(const float4*)(norm_w + e + 4);
    bfrag8 o;
    o[0] = (__bf16)(v[i * 8 + 0] * scale * w0.x);
    o[1] = (__bf16)(v[i * 8 + 1] * scale * w0.y);
    o[2] = (__bf16)(v[i * 8 + 2] * scale * w0.z);
    o[3] = (__bf16)(v[i * 8 + 3] * scale * w0.w);
    o[4] = (__bf16)(v[i * 8 + 4] * scale * w1.x);
    o[5] = (__bf16)(v[i * 8 + 5] * scale * w1.y);
    o[6] = (__bf16)(v[i * 8 + 6] * scale * w1.z);
    o[7] = (__bf16)(v[i * 8 + 7] * scale * w1.w);
    *(bfrag8*)(y + e) = o;
  }
}

// ---------------- launch ----------------
extern "C" void kernel_launch(void* const* d_in, const int* in_sizes, int n_in,
                              void* d_out, int out_size, void* d_ws, size_t ws_size,
                              hipStream_t stream) {
  if (ws_size < WS_NEEDED) return;

  const float* u       = (const float*)d_in[0];
  const float* w_in    = (const float*)d_in[1];
  const float* conv_w  = (const float*)d_in[2];
  const float* conv_b  = (const float*)d_in[3];
  const float* dt_bias = (const float*)d_in[4];
  const float* A_log   = (const float*)d_in[5];
  const float* Dskip   = (const float*)d_in[6];
  const float* norm_w  = (const float*)d_in[7];
  const float* w_out   = (const float*)d_in[8];
  float* out = (float*)d_out;

  char* ws = (char*)d_ws;
  bf16*  win_bf  = (bf16*)(ws + OFF_WIN);
  bf16*  x_bf    = (bf16*)(ws + OFF_XBF);
  bf16*  prevb   = (bf16*)(ws + OFF_PREV);
  bf16*  wout_bf = (bf16*)(ws + OFF_WOUT);
  bf16*  u_bf    = (bf16*)(ws + OFF_UBF);
  float* dtv     = (float*)(ws + OFF_DTV);
  float* dacs    = (float*)(ws + OFF_DACS);
  bf16*  B_bf    = (bf16*)(ws + OFF_BBF);
  bf16*  C_bf    = (bf16*)(ws + OFF_CBF);
  float* CBb     = (float*)(ws + OFF_CB);
  bf16*  BT_bf   = (bf16*)(ws + OFF_BT);
  bf16*  xbc_bf  = (bf16*)(ws + OFF_XBC);
  float* states  = (float*)(ws + OFF_STATE);
  bf16*  z_bf    = (bf16*)(ws + OFF_ZBF);
  float* dt_raw  = (float*)(ws + OFF_DTRAW);
  bf16*  ybuf    = (bf16*)(ws + OFF_YBUF);

  cast_all_kernel<<<25344, 256, 0, stream>>>(u, w_in, u_bf, win_bf);
  gemm1_kernel<<<1152, 512, 0, stream>>>(u_bf, win_bf, z_bf, xbc_bf, dt_raw);
  dt_scan_kernel<<<1024, 256, 0, stream>>>(dt_raw, dt_bias, A_log, dtv, dacs);
  conv_kernel<<<dim3(17, SEQLEN / 8, 2), 256, 0, stream>>>(xbc_bf, conv_w, conv_b, x_bf, B_bf, C_bf, BT_bf);
  cb_kernel<<<64, 256, 0, stream>>>(C_bf, B_bf, CBb);
  ssm_diag_kernel<<<1024, 256, 0, stream>>>(x_bf, BT_bf, CBb, dtv, dacs, Dskip, ybuf, states);
  state_scan_kernel<<<4096, 256, 0, stream>>>(states, dacs, prevb);
  yoff_kernel<<<1024, 256, 0, stream>>>(C_bf, prevb, dacs, ybuf);
  // w_out cast AFTER x_bf (0..33.5MB) is dead; wout slot 16.7..33.5MB is free now.
  cast_kernel<<<8192, 256, 0, stream>>>(w_out, wout_bf, (long)D_MODEL * D_INNER / 4);
  gate_norm_kernel<<<ROWSTOT, 256, 0, stream>>>(ybuf, z_bf, norm_w);
  gemm2_kernel<<<512, 256, 0, stream>>>(ybuf, wout_bf, out);
}